// Round 17
// baseline (111.177 us; speedup 1.0000x reference)
//
#include <hip/hip_runtime.h>
#include <math.h>

#define B  4
#define N  4096
#define C  128
#define K  16
#define NB 3
#define RB 32    // fused: rows per block
#define CH 2048  // knn LDS chunk (points)

typedef unsigned int u32;
typedef unsigned long long u64;
typedef __attribute__((ext_vector_type(8))) short short8_t;
typedef __attribute__((ext_vector_type(4))) float f32x4;

__device__ __forceinline__ float leaky(float x) {
  return x >= 0.f ? x : 0.01f * x;
}
__device__ __forceinline__ unsigned short f2bf(float f) {
  u32 x = __float_as_uint(f);
  return (unsigned short)((x + 0x7FFFu + ((x >> 16) & 1u)) >> 16);  // RNE
}
__device__ __forceinline__ float bflo(u32 u) { return __uint_as_float(u << 16); }
__device__ __forceinline__ float bfhi(u32 u) { return __uint_as_float(u & 0xFFFF0000u); }
__device__ __forceinline__ u32 umaxu(u32 a, u32 b) { return a > b ? a : b; }

// XCD-pair swizzle: bidx=(q*8+x) -> batch b=x>>1, row-group rgrp=2q+(x&1).
__device__ __forceinline__ void swz_batch(int bidx, int* b, int* rgrp) {
  int q = bidx >> 3, x = bidx & 7;
  *b = x >> 1;
  *rgrp = (q << 1) | (x & 1);
}

// 64-lane max reduce, pure VALU via DPP. Result valid in lane 63.
__device__ __forceinline__ u32 dpp_max64(u32 v) {
  v = umaxu(v, (u32)__builtin_amdgcn_update_dpp(0, (int)v, 0x111, 0xf, 0xf, false));
  v = umaxu(v, (u32)__builtin_amdgcn_update_dpp(0, (int)v, 0x112, 0xf, 0xf, false));
  v = umaxu(v, (u32)__builtin_amdgcn_update_dpp(0, (int)v, 0x114, 0xf, 0xf, false));
  v = umaxu(v, (u32)__builtin_amdgcn_update_dpp(0, (int)v, 0x118, 0xf, 0xf, false));
  v = umaxu(v, (u32)__builtin_amdgcn_update_dpp(0, (int)v, 0x142, 0xa, 0xf, false));
  v = umaxu(v, (u32)__builtin_amdgcn_update_dpp(0, (int)v, 0x143, 0xc, 0xf, false));
  return v;
}

// exact monotone-encoded squared distance (reference op order, no contraction)
__device__ __forceinline__ u32 encdist(float xi, float yi, float zi, float sqi,
                                       float4 pj) {
  float dt = __fadd_rn(__fmul_rn(xi, pj.x), __fmul_rn(yi, pj.y));
  dt = __fadd_rn(dt, __fmul_rn(zi, pj.z));
  float dd = __fsub_rn(__fadd_rn(sqi, pj.w), __fmul_rn(2.0f, dt));
  u32 bits = __float_as_uint(dd);
  return bits ^ ((u32)(((int)bits) >> 31) | 0x80000000u);
}

// cheap approximate distance (fma contraction allowed), clamped to >= 0.
// Used ONLY for the tau threshold / survivor predicate (1-quantum slack);
// exact encdist is recomputed for all survivors.
__device__ __forceinline__ float apxdist(float xi, float yi, float zi, float sqi,
                                         float4 pj) {
  float dd = (sqi + pj.w) - 2.0f * (xi * pj.x + (yi * pj.y + zi * pj.z));
  return fmaxf(dd, 0.0f);
}

// ---- prep: pxyzw[e] = (x, y, z, sq_exact) once per point ----
// (previously each knn block recomputed sq for all 4096 points -> 512x waste)
__global__ __launch_bounds__(256) void prep_kernel(const float* __restrict__ xyz,
                                                   float4* __restrict__ pxyzw) {
  int e = blockIdx.x * 256 + threadIdx.x;  // 0..B*N-1
  float x = xyz[3 * e], y = xyz[3 * e + 1], z = xyz[3 * e + 2];
  // sq = (x*x + y*y) + z*z, exact f32 rounding, no FMA contraction
  float sq = __fadd_rn(__fadd_rn(__fmul_rn(x, x), __fmul_rn(y, y)), __fmul_rn(z, z));
  pxyzw[e] = make_float4(x, y, z, sq);
}

// ---- KNN (faithful: k+1 LARGEST sq-dists, drop first) ----
// 2048 blocks x 512 threads (8 waves). ONE wave per row, 64 candidates/lane.
// Cloud staged in TWO 32KB chunks from the precomputed pxyzw table -> LDS
// 36KB -> 4 blocks/CU -> 32 waves/CU (r16 was 68KB -> 2 blocks -> 37% occ,
// latency-bound at VALUBusy 60%). Threshold-select (r15/r16 scheme):
//  A: APPROX distances (fma-contracted); hi16 packed 2/reg; float lane max.
//  B: bitonic sort of 64 lane-max bit-patterns; tau16 = hi16(17th) - 1
//     (slack covers fma-vs-exact error << bf16 quantum -> superset proof).
//  C: predicate hi16(approx) >= tau16; ballot-compact; survivors recompute
//     EXACT enc from GLOBAL pxyzw (L2-resident; ~20 reads/row).
//  D: bitonic sort survivors; ranks 1..16 output (rank 0 = dropped max).
// Key (enc<<32)|(4095-j) == jax top_k order (value desc, index asc).
// Fallback if total > 64 (degenerate/tied data): exact iterative extract
// reading global pxyzw.
__global__ __launch_bounds__(512) void knn_kernel(const float4* __restrict__ pxyzw,
                                                  int* __restrict__ idxOut) {
  __shared__ float4 p[CH];      // 32 KB
  __shared__ u64 surv[8][64];   // 4 KB survivor buffer, per wave
  int bidx = blockIdx.x;
  int b = bidx >> 9;            // 512 blocks per batch
  int row0 = (bidx & 511) << 3; // 8 rows per block
  const float4* pb = pxyzw + ((size_t)b << 12);
  int tid = threadIdx.x;
  int lane = tid & 63;
  int wave = tid >> 6;   // 0..7 = local row
  int i = row0 + wave;   // query point within batch

  float4 pi = pb[i];
  float xi = pi.x, yi = pi.y, zi = pi.z, sqi = pi.w;

  // Phase A: approx distances per 32KB chunk; pack hi16; float running max
  u32 denc16[32];
  float fmx = 0.0f;
#pragma unroll
  for (int ch = 0; ch < 2; ++ch) {
    __syncthreads();  // protect previous chunk's reads before overwrite
    for (int e = tid; e < CH; e += 512) p[e] = pb[(ch << 11) + e];
    __syncthreads();
#pragma unroll
    for (int tl2 = 0; tl2 < 16; ++tl2) {
      int t2 = (ch << 4) | tl2;  // compile-time after unroll
      float4 pj0 = p[lane + ((tl2 * 2) << 6)];
      float4 pj1 = p[lane + ((tl2 * 2 + 1) << 6)];
      float d0 = apxdist(xi, yi, zi, sqi, pj0);
      float d1 = apxdist(xi, yi, zi, sqi, pj1);
      fmx = fmaxf(fmx, fmaxf(d0, d1));
      denc16[t2] = (__float_as_uint(d0) >> 16) | (__float_as_uint(d1) & 0xFFFF0000u);
    }
  }

  // Phase B: sort the 64 lane-max values (u32 bits, all >= +0) descending
  u32 sv = __float_as_uint(fmx);
#pragma unroll
  for (int k2 = 2; k2 <= 64; k2 <<= 1) {
#pragma unroll
    for (int jj = k2 >> 1; jj > 0; jj >>= 1) {
      u32 ov = (u32)__shfl_xor((int)sv, jj, 64);
      bool keepMax = ((lane & jj) == 0) == ((lane & k2) == 0);
      sv = (keepMax == (ov > sv)) ? ov : sv;
    }
  }
  u32 th = ((u32)__shfl((int)sv, 16, 64)) >> 16;
  u32 tau16 = (th > 0u) ? (th - 1u) : 0u;  // 1-quantum slack (superset)

  // Phase C: ballot-compact candidates with hi16(approx) >= tau16;
  // survivors recompute exact enc from GLOBAL pxyzw (L2-hit)
  int total = 0;
#pragma unroll
  for (int t = 0; t < 64; ++t) {
    u32 h = (t & 1) ? (denc16[t >> 1] >> 16) : (denc16[t >> 1] & 0xFFFFu);
    bool pred = (h >= tau16);
    u64 bal = __ballot(pred);
    if (bal != 0ull) {  // wave-uniform skip of empty slots
      int pos = total + (int)__builtin_amdgcn_mbcnt_hi(
                            (u32)(bal >> 32),
                            __builtin_amdgcn_mbcnt_lo((u32)bal, 0u));
      if (pred && pos < 64) {
        u32 enc = encdist(xi, yi, zi, sqi, pb[lane + (t << 6)]);  // exact
        surv[wave][pos] = ((u64)enc << 32) | (u32)(4095 - (lane + (t << 6)));
      }
      total += (int)__popcll(bal);
    }
  }

  if (total <= 64) {
    // Phase D: sort survivors descending (zeros pad to the end), emit 1..16.
    u64 sk = (lane < total) ? surv[wave][lane] : 0ull;
#pragma unroll
    for (int k2 = 2; k2 <= 64; k2 <<= 1) {
#pragma unroll
      for (int jj = k2 >> 1; jj > 0; jj >>= 1) {
        u64 ok = __shfl_xor(sk, jj, 64);
        bool keepMax = ((lane & jj) == 0) == ((lane & k2) == 0);
        sk = (keepMax == (ok > sk)) ? ok : sk;
      }
    }
    if (lane >= 1 && lane < 17) {
      idxOut[((long long)(b * N + i)) * K + lane - 1] = 4095 - (int)(u32)sk;
    }
  } else {
    // Fallback (degenerate ties; never on this input): exact iterative
    // extraction reading global pxyzw.
    u32 cmax = 0u; u32 ct = 0u;
#pragma unroll
    for (int t = 0; t < 64; ++t) {
      u32 enc = encdist(xi, yi, zi, sqi, pb[lane + (t << 6)]);
      if (enc > cmax) { cmax = enc; ct = (u32)t; }
    }
    u64 elim = 0ull;
    for (int r = 0; r < 17; ++r) {
      u32 wmax = dpp_max64(cmax);
      u32 s_wmax = (u32)__builtin_amdgcn_readlane((int)wmax, 63);
      u64 mask = __ballot(cmax == s_wmax);
      int s_wj;
      if (__popcll(mask) == 1) {
        int l = (int)(__ffsll((long long)mask) - 1);
        int myj = lane + ((int)ct << 6);
        s_wj = __builtin_amdgcn_readlane(myj, l);
      } else {
        u32 jv = (cmax == s_wmax) ? (u32)(lane + ((int)ct << 6)) : 0xFFFFFFFFu;
#pragma unroll
        for (int off = 1; off < 64; off <<= 1) {
          u32 oj = (u32)__shfl_xor((int)jv, off, 64);
          jv = oj < jv ? oj : jv;
        }
        s_wj = (int)__builtin_amdgcn_readfirstlane((int)jv);
      }
      if (r > 0 && lane == 0)
        idxOut[((long long)(b * N + i)) * K + (r - 1)] = s_wj;
      if (r == 16) break;
      if (lane == (s_wj & 63)) {
        elim |= 1ull << (s_wj >> 6);
        cmax = 0u; ct = 0u;
        for (int t = 0; t < 64; ++t) {
          if (elim & (1ull << t)) continue;
          u32 enc = encdist(xi, yi, zi, sqi, pb[lane + (t << 6)]);
          if (enc > cmax) { cmax = enc; ct = (u32)t; }
        }
      }
    }
  }
}

// ---- Abf = bf16(leaky(P)) : XCD-pair swizzled (1024 blocks x 256) ----
__global__ __launch_bounds__(256) void cvtA_kernel(const float* __restrict__ P,
                                                   unsigned short* __restrict__ Abf) {
  int b, rgrp;
  swz_batch(blockIdx.x, &b, &rgrp);
  int tid = threadIdx.x;
  size_t off = ((size_t)b * N + rgrp * 16 + (tid >> 4)) * C + (tid & 15) * 8;
  const float4* p4 = (const float4*)(P + off);
  float4 a = p4[0], c = p4[1];
  unsigned short u0 = f2bf(leaky(a.x)), u1 = f2bf(leaky(a.y));
  unsigned short u2 = f2bf(leaky(a.z)), u3 = f2bf(leaky(a.w));
  unsigned short u4 = f2bf(leaky(c.x)), u5 = f2bf(leaky(c.y));
  unsigned short u6 = f2bf(leaky(c.z)), u7 = f2bf(leaky(c.w));
  uint4 o;
  o.x = (u32)u0 | ((u32)u1 << 16);
  o.y = (u32)u2 | ((u32)u3 << 16);
  o.z = (u32)u4 | ((u32)u5 << 16);
  o.w = (u32)u6 | ((u32)u7 << 16);
  *(uint4*)(Abf + off) = o;
}

// ---- W (f32) -> bf16, all 3 blocks at once ----
__global__ __launch_bounds__(256) void cvtW_kernel(const float* __restrict__ Wc,
                                                   const float* __restrict__ Wg,
                                                   unsigned short* __restrict__ Wbf) {
  int e = blockIdx.x * 256 + threadIdx.x;  // 0..98303
  if (e < NB * C * C) Wbf[e] = f2bf(Wc[e]);
  else Wbf[e] = f2bf(Wg[e - NB * C * C]);
}

// ---- fused per-block-iter: gather-sum (bf16) + dual MFMA matmul + epilogue
// 512 blocks x 512 threads (8 waves), XCD-pair swizzled. Block = RB=32 rows.
// Wave w = col-tile w (16 cols) x 2 row-tiles. LDS-staged coalesced epilogue.
__global__ __launch_bounds__(512) void fused_kernel(
    const float* __restrict__ Pcur, const unsigned short* __restrict__ Abf,
    const int* __restrict__ idx,
    const unsigned short* __restrict__ Wcbf, const unsigned short* __restrict__ Wgbf,
    const float* __restrict__ bc, const float* __restrict__ bg,
    float* __restrict__ Pnxt, unsigned short* __restrict__ AbfN) {
  __shared__ int ji[RB * K];              // 2 KB
  __shared__ unsigned short Sl[RB][136];  // 8.7 KB (+8 pad)
  __shared__ float Pst[RB][128];          // 16 KB epilogue staging
  int bb, rgrp;
  swz_batch(blockIdx.x, &bb, &rgrp);      // 512 blocks: rgrp 0..127
  int row0 = bb * N + rgrp * RB;          // global row
  int tid = threadIdx.x;
  ji[tid] = idx[row0 * K + tid];          // RB*K = 512 = blockDim
  __syncthreads();

  // batch base for neighbor indices (idx entries are within-batch!)
  const unsigned short* AbfB = Abf + ((size_t)bb << 12) * C;

  // gather: thread (r,g) sums 8 cols [g*8, g*8+8) of row r over 16 neighbors
  {
    int r = tid >> 4, g = tid & 15;  // r 0..31
    float s0 = 0.f, s1 = 0.f, s2 = 0.f, s3 = 0.f, s4 = 0.f, s5 = 0.f, s6 = 0.f, s7 = 0.f;
#pragma unroll
    for (int t = 0; t < K; ++t) {
      int j = ji[(r << 4) + t];
      uint4 v = *(const uint4*)(AbfB + (size_t)j * C + g * 8);
      s0 += bflo(v.x); s1 += bfhi(v.x);
      s2 += bflo(v.y); s3 += bfhi(v.y);
      s4 += bflo(v.z); s5 += bfhi(v.z);
      s6 += bflo(v.w); s7 += bfhi(v.w);
    }
    uint4 o;
    o.x = (u32)f2bf(s0) | ((u32)f2bf(s1) << 16);
    o.y = (u32)f2bf(s2) | ((u32)f2bf(s3) << 16);
    o.z = (u32)f2bf(s4) | ((u32)f2bf(s5) << 16);
    o.w = (u32)f2bf(s6) | ((u32)f2bf(s7) << 16);
    *(uint4*)(&Sl[r][g * 8]) = o;
  }
  __syncthreads();

  // MFMA: wave = col-tile ct (16 cols); 2 row-tiles (rows 0-15, 16-31).
  // A row = lane&15, k-chunk = (lane>>4)*8 ; B col = lane&15, same k-chunk.
  int lane = tid & 63, wave = tid >> 6;  // 8 waves
  int lrow = lane & 15;
  int kgrp = (lane >> 4) * 8;
  int ct = wave;
  f32x4 acc0 = {0.f, 0.f, 0.f, 0.f};
  f32x4 acc1 = {0.f, 0.f, 0.f, 0.f};
  const unsigned short* a0p = Abf + (size_t)(row0 + lrow) * C + kgrp;
  const unsigned short* a1p = Abf + (size_t)(row0 + 16 + lrow) * C + kgrp;
  const unsigned short* wcp = Wcbf + (size_t)(ct * 16 + lrow) * C + kgrp;
  const unsigned short* wgp = Wgbf + (size_t)(ct * 16 + lrow) * C + kgrp;
#pragma unroll
  for (int ks = 0; ks < 4; ++ks) {
    short8_t bC = *(const short8_t*)(wcp + ks * 32);
    short8_t av0 = *(const short8_t*)(a0p + ks * 32);
    short8_t av1 = *(const short8_t*)(a1p + ks * 32);
    acc0 = __builtin_amdgcn_mfma_f32_16x16x32_bf16(av0, bC, acc0, 0, 0, 0);
    acc1 = __builtin_amdgcn_mfma_f32_16x16x32_bf16(av1, bC, acc1, 0, 0, 0);
  }
#pragma unroll
  for (int ks = 0; ks < 4; ++ks) {
    short8_t bG = *(const short8_t*)(wgp + ks * 32);
    short8_t sv0 = *(const short8_t*)(&Sl[lrow][kgrp + ks * 32]);
    short8_t sv1 = *(const short8_t*)(&Sl[16 + lrow][kgrp + ks * 32]);
    acc0 = __builtin_amdgcn_mfma_f32_16x16x32_bf16(sv0, bG, acc0, 0, 0, 0);
    acc1 = __builtin_amdgcn_mfma_f32_16x16x32_bf16(sv1, bG, acc1, 0, 0, 0);
  }

  // stage fragments: D row=(lane>>4)*4+q, col=lane&15 (within 16x16 tile)
  {
    int colw = ct * 16 + lrow;
    int rbase = (lane >> 4) * 4;
#pragma unroll
    for (int q = 0; q < 4; ++q) {
      Pst[rbase + q][colw] = acc0[q];
      Pst[16 + rbase + q][colw] = acc1[q];
    }
  }
  __syncthreads();

  // coalesced epilogue: thread -> (row, 8 cols); float4/uint4 global I/O
  {
    int r = tid >> 4;           // 0..31
    int c8 = (tid & 15) * 8;
    size_t goff = (size_t)(row0 + r) * C + c8;
    float4 av = *(const float4*)&Pst[r][c8];
    float4 aw = *(const float4*)&Pst[r][c8 + 4];
    float4 bcv0 = *(const float4*)&bc[c8];
    float4 bcv1 = *(const float4*)&bc[c8 + 4];
    float4 bgv0 = *(const float4*)&bg[c8];
    float4 bgv1 = *(const float4*)&bg[c8 + 4];
    float4 pv0 = *(const float4*)&Pcur[goff];
    float4 pv1 = *(const float4*)&Pcur[goff + 4];
    float4 o0, o1;
    o0.x = (av.x + (bcv0.x + 16.0f * bgv0.x)) * (1.0f / 17.0f) + pv0.x;
    o0.y = (av.y + (bcv0.y + 16.0f * bgv0.y)) * (1.0f / 17.0f) + pv0.y;
    o0.z = (av.z + (bcv0.z + 16.0f * bgv0.z)) * (1.0f / 17.0f) + pv0.z;
    o0.w = (av.w + (bcv0.w + 16.0f * bgv0.w)) * (1.0f / 17.0f) + pv0.w;
    o1.x = (aw.x + (bcv1.x + 16.0f * bgv1.x)) * (1.0f / 17.0f) + pv1.x;
    o1.y = (aw.y + (bcv1.y + 16.0f * bgv1.y)) * (1.0f / 17.0f) + pv1.y;
    o1.z = (aw.z + (bcv1.z + 16.0f * bgv1.z)) * (1.0f / 17.0f) + pv1.z;
    o1.w = (aw.w + (bcv1.w + 16.0f * bgv1.w)) * (1.0f / 17.0f) + pv1.w;
    *(float4*)&Pnxt[goff] = o0;
    *(float4*)&Pnxt[goff + 4] = o1;
    if (AbfN) {
      uint4 ob;
      ob.x = (u32)f2bf(leaky(o0.x)) | ((u32)f2bf(leaky(o0.y)) << 16);
      ob.y = (u32)f2bf(leaky(o0.z)) | ((u32)f2bf(leaky(o0.w)) << 16);
      ob.z = (u32)f2bf(leaky(o1.x)) | ((u32)f2bf(leaky(o1.y)) << 16);
      ob.w = (u32)f2bf(leaky(o1.z)) | ((u32)f2bf(leaky(o1.w)) << 16);
      *(uint4*)(AbfN + goff) = ob;
    }
  }
}

extern "C" void kernel_launch(void* const* d_in, const int* in_sizes, int n_in,
                              void* d_out, int out_size, void* d_ws, size_t ws_size,
                              hipStream_t stream) {
  const float* xyz = (const float*)d_in[0];
  const float* pts = (const float*)d_in[1];
  const float* Wc = (const float*)d_in[5];
  const float* bc = (const float*)d_in[6];
  const float* Wg = (const float*)d_in[7];
  const float* bg = (const float*)d_in[8];

  const size_t PE = (size_t)B * N * C;            // 2097152 elements
  const size_t idxB = (size_t)B * N * K * 4;      // 1 MB
  const size_t WbfB = (size_t)2 * NB * C * C * 2; // 192 KB
  const size_t pxB  = (size_t)B * N * 16;         // 256 KB
  char* ws = (char*)d_ws;
  float* Pa            = (float*)ws;                                  // 8 MB
  int* idx             = (int*)(ws + PE * 4);                         // 1 MB
  unsigned short* Abf0 = (unsigned short*)(ws + PE * 4 + idxB);       // 4 MB
  unsigned short* Wbf  = (unsigned short*)(ws + PE * 4 + idxB + PE * 2);
  float4* pxyzw        = (float4*)(ws + PE * 4 + idxB + PE * 2 + WbfB);
  unsigned short* Abf1 = (unsigned short*)(ws + PE * 4 + idxB + PE * 2 + WbfB + pxB);
  unsigned short* Wcbf = Wbf;
  unsigned short* Wgbf = Wbf + (size_t)NB * C * C;
  const size_t need = PE * 4 + idxB + PE * 2 + WbfB + pxB + PE * 2;  // 17.4 MB
  const bool fusedAbf = (ws_size >= need);

  hipLaunchKernelGGL(prep_kernel, dim3((B * N) / 256), dim3(256), 0, stream,
                     xyz, pxyzw);
  hipLaunchKernelGGL(cvtW_kernel, dim3((2 * NB * C * C) / 256), dim3(256), 0, stream,
                     Wc, Wg, Wbf);
  hipLaunchKernelGGL(cvtA_kernel, dim3(1024), dim3(256), 0, stream, pts, Abf0);
  hipLaunchKernelGGL(knn_kernel, dim3(2048), dim3(512), 0, stream, pxyzw, idx);

  // ping-pong: pts (read-only) -> d_out -> Pa -> d_out
  const float* cur = pts;
  float* nxt = (float*)d_out;
  unsigned short* AbfCur = Abf0;
  unsigned short* AbfNxt = fusedAbf ? Abf1 : Abf0;
  for (int i = 0; i < NB; ++i) {
    if (!fusedAbf && i > 0) {
      hipLaunchKernelGGL(cvtA_kernel, dim3(1024), dim3(256), 0, stream, cur, Abf0);
      AbfCur = Abf0;
    }
    unsigned short* an = (fusedAbf && i < NB - 1) ? AbfNxt : (unsigned short*)nullptr;
    hipLaunchKernelGGL(fused_kernel, dim3((B * N) / RB), dim3(512), 0, stream,
                       cur, AbfCur, idx, Wcbf + (size_t)i * C * C, Wgbf + (size_t)i * C * C,
                       bc + (size_t)i * C, bg + (size_t)i * C, nxt, an);
    cur = nxt;
    nxt = (i == 0) ? Pa : (float*)d_out;
    if (fusedAbf) { unsigned short* ta = AbfCur; AbfCur = AbfNxt; AbfNxt = ta; }
  }
}

// Round 18
// 100.597 us; speedup vs baseline: 1.1052x; 1.1052x over previous
//
#include <hip/hip_runtime.h>
#include <math.h>

#define B  4
#define N  4096
#define C  128
#define K  16
#define NB 3
#define RB 32  // fused: rows per block

typedef unsigned int u32;
typedef unsigned long long u64;
typedef __attribute__((ext_vector_type(8))) short short8_t;
typedef __attribute__((ext_vector_type(4))) float f32x4;

__device__ __forceinline__ float leaky(float x) {
  return x >= 0.f ? x : 0.01f * x;
}
__device__ __forceinline__ unsigned short f2bf(float f) {
  u32 x = __float_as_uint(f);
  return (unsigned short)((x + 0x7FFFu + ((x >> 16) & 1u)) >> 16);  // RNE
}
__device__ __forceinline__ float bflo(u32 u) { return __uint_as_float(u << 16); }
__device__ __forceinline__ float bfhi(u32 u) { return __uint_as_float(u & 0xFFFF0000u); }
__device__ __forceinline__ u32 umaxu(u32 a, u32 b) { return a > b ? a : b; }

// XCD-pair swizzle: bidx=(q*8+x) -> batch b=x>>1, row-group rgrp=2q+(x&1).
__device__ __forceinline__ void swz_batch(int bidx, int* b, int* rgrp) {
  int q = bidx >> 3, x = bidx & 7;
  *b = x >> 1;
  *rgrp = (q << 1) | (x & 1);
}

// 64-lane max reduce, pure VALU via DPP. Result valid in lane 63.
__device__ __forceinline__ u32 dpp_max64(u32 v) {
  v = umaxu(v, (u32)__builtin_amdgcn_update_dpp(0, (int)v, 0x111, 0xf, 0xf, false));
  v = umaxu(v, (u32)__builtin_amdgcn_update_dpp(0, (int)v, 0x112, 0xf, 0xf, false));
  v = umaxu(v, (u32)__builtin_amdgcn_update_dpp(0, (int)v, 0x114, 0xf, 0xf, false));
  v = umaxu(v, (u32)__builtin_amdgcn_update_dpp(0, (int)v, 0x118, 0xf, 0xf, false));
  v = umaxu(v, (u32)__builtin_amdgcn_update_dpp(0, (int)v, 0x142, 0xa, 0xf, false));
  v = umaxu(v, (u32)__builtin_amdgcn_update_dpp(0, (int)v, 0x143, 0xc, 0xf, false));
  return v;
}

// exact monotone-encoded squared distance (reference op order, no contraction)
__device__ __forceinline__ u32 encdist(float xi, float yi, float zi, float sqi,
                                       float4 pj) {
  float dt = __fadd_rn(__fmul_rn(xi, pj.x), __fmul_rn(yi, pj.y));
  dt = __fadd_rn(dt, __fmul_rn(zi, pj.z));
  float dd = __fsub_rn(__fadd_rn(sqi, pj.w), __fmul_rn(2.0f, dt));
  u32 bits = __float_as_uint(dd);
  return bits ^ ((u32)(((int)bits) >> 31) | 0x80000000u);
}

// cheap approximate distance (fma contraction allowed), clamped to >= 0.
// Used ONLY for the tau threshold / survivor predicate (with 1-quantum slack);
// exact encdist is recomputed for all survivors.
__device__ __forceinline__ float apxdist(float xi, float yi, float zi, float sqi,
                                         float4 pj) {
  float dd = (sqi + pj.w) - 2.0f * (xi * pj.x + (yi * pj.y + zi * pj.z));
  return fmaxf(dd, 0.0f);
}

// ---- KNN (faithful: k+1 LARGEST sq-dists, drop first) ----
// Round-16 version verbatim (best measured: 47.7us, VGPR 52). 2048 blocks x
// 512 threads (8 waves). ONE wave per row, 64 candidates/lane; single 64KB
// stage keeps Phase A an unbroken load/compute stream (r17's chunk-split
// with barriers regressed 15us despite lower LDS). Threshold-select:
//  A: APPROX distances (fma-contracted, ~5 VALU vs 13 exact); hi-16 packed
//     2/reg; float running max (no index).
//  B: bitonic sort of the 64 lane-max f32 bit-patterns -> tau = 17th largest;
//     tau16 = hi16(tau) - 1 (slack >> fma-vs-exact error -> superset proof).
//  C: predicate hi16(approx) >= tau16; ballot-compact; survivors recompute
//     EXACT enc (reference op order); store exact u64 key to LDS.
//  D: bitonic sort survivors; ranks 1..16 output (rank 0 = dropped max).
// Key (enc<<32)|(4095-j) == jax top_k order (value desc, index asc).
// Fallback if total > 64 (degenerate/tied data): exact iterative extract.
__global__ __launch_bounds__(512) void knn_kernel(const float* __restrict__ xyz,
                                                  int* __restrict__ idxOut) {
  __shared__ float4 p[N];       // 64 KB
  __shared__ u64 surv[8][64];   // 4 KB survivor buffer, per wave
  int bidx = blockIdx.x;
  int b = bidx >> 9;            // 512 blocks per batch
  int row0 = (bidx & 511) << 3; // 8 rows per block
  const float* src = xyz + b * N * 3;
  int tid = threadIdx.x;

  for (int e = tid; e < N; e += 512) {
    float x = src[3 * e], y = src[3 * e + 1], z = src[3 * e + 2];
    // sq = (x*x + y*y) + z*z, exact f32 rounding, no FMA contraction
    float sq = __fadd_rn(__fadd_rn(__fmul_rn(x, x), __fmul_rn(y, y)), __fmul_rn(z, z));
    p[e] = make_float4(x, y, z, sq);
  }
  __syncthreads();

  int lane = tid & 63;
  int wave = tid >> 6;   // 0..7 = local row
  int i = row0 + wave;   // query point within batch

  float4 pi = p[i];
  float xi = pi.x, yi = pi.y, zi = pi.z, sqi = pi.w;

  // Phase A: approx distances; pack hi16; float running max
  u32 denc16[32];
  float fmx = 0.0f;
#pragma unroll
  for (int t2 = 0; t2 < 32; ++t2) {
    int t0 = t2 * 2, t1 = t0 + 1;
    float4 pj0 = p[lane + (t0 << 6)];
    float4 pj1 = p[lane + (t1 << 6)];
    float d0 = apxdist(xi, yi, zi, sqi, pj0);
    float d1 = apxdist(xi, yi, zi, sqi, pj1);
    fmx = fmaxf(fmx, fmaxf(d0, d1));
    denc16[t2] = (__float_as_uint(d0) >> 16) | (__float_as_uint(d1) & 0xFFFF0000u);
  }

  // Phase B: sort the 64 lane-max values (u32 bits, all >= +0) descending
  u32 sv = __float_as_uint(fmx);
#pragma unroll
  for (int k2 = 2; k2 <= 64; k2 <<= 1) {
#pragma unroll
    for (int jj = k2 >> 1; jj > 0; jj >>= 1) {
      u32 ov = (u32)__shfl_xor((int)sv, jj, 64);
      bool keepMax = ((lane & jj) == 0) == ((lane & k2) == 0);
      sv = (keepMax == (ov > sv)) ? ov : sv;
    }
  }
  u32 th = ((u32)__shfl((int)sv, 16, 64)) >> 16;
  u32 tau16 = (th > 0u) ? (th - 1u) : 0u;  // 1-quantum slack (superset)

  // Phase C: ballot-compact candidates with hi16(approx) >= tau16; exact keys
  int total = 0;
#pragma unroll
  for (int t = 0; t < 64; ++t) {
    u32 h = (t & 1) ? (denc16[t >> 1] >> 16) : (denc16[t >> 1] & 0xFFFFu);
    bool pred = (h >= tau16);
    u64 bal = __ballot(pred);
    if (bal != 0ull) {  // wave-uniform skip of empty slots
      int pos = total + (int)__builtin_amdgcn_mbcnt_hi(
                            (u32)(bal >> 32),
                            __builtin_amdgcn_mbcnt_lo((u32)bal, 0u));
      if (pred && pos < 64) {
        u32 enc = encdist(xi, yi, zi, sqi, p[lane + (t << 6)]);  // exact
        surv[wave][pos] = ((u64)enc << 32) | (u32)(4095 - (lane + (t << 6)));
      }
      total += (int)__popcll(bal);
    }
  }

  if (total <= 64) {
    // Phase D: sort survivors descending (zeros pad to the end), emit 1..16.
    u64 sk = (lane < total) ? surv[wave][lane] : 0ull;
#pragma unroll
    for (int k2 = 2; k2 <= 64; k2 <<= 1) {
#pragma unroll
      for (int jj = k2 >> 1; jj > 0; jj >>= 1) {
        u64 ok = __shfl_xor(sk, jj, 64);
        bool keepMax = ((lane & jj) == 0) == ((lane & k2) == 0);
        sk = (keepMax == (ok > sk)) ? ok : sk;
      }
    }
    if (lane >= 1 && lane < 17) {
      idxOut[((long long)(b * N + i)) * K + lane - 1] = 4095 - (int)(u32)sk;
    }
  } else {
    // Fallback (degenerate ties; never on this input): exact iterative
    // extraction; recomputes its own exact argmax first.
    u32 cmax = 0u; u32 ct = 0u;
#pragma unroll
    for (int t = 0; t < 64; ++t) {
      u32 enc = encdist(xi, yi, zi, sqi, p[lane + (t << 6)]);
      if (enc > cmax) { cmax = enc; ct = (u32)t; }
    }
    u64 elim = 0ull;
    for (int r = 0; r < 17; ++r) {
      u32 wmax = dpp_max64(cmax);
      u32 s_wmax = (u32)__builtin_amdgcn_readlane((int)wmax, 63);
      u64 mask = __ballot(cmax == s_wmax);
      int s_wj;
      if (__popcll(mask) == 1) {
        int l = (int)(__ffsll((long long)mask) - 1);
        int myj = lane + ((int)ct << 6);
        s_wj = __builtin_amdgcn_readlane(myj, l);
      } else {
        u32 jv = (cmax == s_wmax) ? (u32)(lane + ((int)ct << 6)) : 0xFFFFFFFFu;
#pragma unroll
        for (int off = 1; off < 64; off <<= 1) {
          u32 oj = (u32)__shfl_xor((int)jv, off, 64);
          jv = oj < jv ? oj : jv;
        }
        s_wj = (int)__builtin_amdgcn_readfirstlane((int)jv);
      }
      if (r > 0 && lane == 0)
        idxOut[((long long)(b * N + i)) * K + (r - 1)] = s_wj;
      if (r == 16) break;
      if (lane == (s_wj & 63)) {
        elim |= 1ull << (s_wj >> 6);
        cmax = 0u; ct = 0u;
        for (int t = 0; t < 64; ++t) {
          if (elim & (1ull << t)) continue;
          u32 enc = encdist(xi, yi, zi, sqi, p[lane + (t << 6)]);
          if (enc > cmax) { cmax = enc; ct = (u32)t; }
        }
      }
    }
  }
}

// ---- Abf = bf16(leaky(P)) : XCD-pair swizzled (1024 blocks x 256) ----
__global__ __launch_bounds__(256) void cvtA_kernel(const float* __restrict__ P,
                                                   unsigned short* __restrict__ Abf) {
  int b, rgrp;
  swz_batch(blockIdx.x, &b, &rgrp);
  int tid = threadIdx.x;
  size_t off = ((size_t)b * N + rgrp * 16 + (tid >> 4)) * C + (tid & 15) * 8;
  const float4* p4 = (const float4*)(P + off);
  float4 a = p4[0], c = p4[1];
  unsigned short u0 = f2bf(leaky(a.x)), u1 = f2bf(leaky(a.y));
  unsigned short u2 = f2bf(leaky(a.z)), u3 = f2bf(leaky(a.w));
  unsigned short u4 = f2bf(leaky(c.x)), u5 = f2bf(leaky(c.y));
  unsigned short u6 = f2bf(leaky(c.z)), u7 = f2bf(leaky(c.w));
  uint4 o;
  o.x = (u32)u0 | ((u32)u1 << 16);
  o.y = (u32)u2 | ((u32)u3 << 16);
  o.z = (u32)u4 | ((u32)u5 << 16);
  o.w = (u32)u6 | ((u32)u7 << 16);
  *(uint4*)(Abf + off) = o;
}

// ---- W (f32) -> bf16, all 3 blocks at once ----
__global__ __launch_bounds__(256) void cvtW_kernel(const float* __restrict__ Wc,
                                                   const float* __restrict__ Wg,
                                                   unsigned short* __restrict__ Wbf) {
  int e = blockIdx.x * 256 + threadIdx.x;  // 0..98303
  if (e < NB * C * C) Wbf[e] = f2bf(Wc[e]);
  else Wbf[e] = f2bf(Wg[e - NB * C * C]);
}

// ---- fused per-block-iter: gather-sum (bf16) + dual MFMA matmul + epilogue
// 512 blocks x 512 threads (8 waves), XCD-pair swizzled. Block = RB=32 rows.
// Wave w = col-tile w (16 cols) x 2 row-tiles. LDS-staged coalesced epilogue.
__global__ __launch_bounds__(512) void fused_kernel(
    const float* __restrict__ Pcur, const unsigned short* __restrict__ Abf,
    const int* __restrict__ idx,
    const unsigned short* __restrict__ Wcbf, const unsigned short* __restrict__ Wgbf,
    const float* __restrict__ bc, const float* __restrict__ bg,
    float* __restrict__ Pnxt, unsigned short* __restrict__ AbfN) {
  __shared__ int ji[RB * K];              // 2 KB
  __shared__ unsigned short Sl[RB][136];  // 8.7 KB (+8 pad)
  __shared__ float Pst[RB][128];          // 16 KB epilogue staging
  int bb, rgrp;
  swz_batch(blockIdx.x, &bb, &rgrp);      // 512 blocks: rgrp 0..127
  int row0 = bb * N + rgrp * RB;          // global row
  int tid = threadIdx.x;
  ji[tid] = idx[row0 * K + tid];          // RB*K = 512 = blockDim
  __syncthreads();

  // batch base for neighbor indices (idx entries are within-batch!)
  const unsigned short* AbfB = Abf + ((size_t)bb << 12) * C;

  // gather: thread (r,g) sums 8 cols [g*8, g*8+8) of row r over 16 neighbors
  {
    int r = tid >> 4, g = tid & 15;  // r 0..31
    float s0 = 0.f, s1 = 0.f, s2 = 0.f, s3 = 0.f, s4 = 0.f, s5 = 0.f, s6 = 0.f, s7 = 0.f;
#pragma unroll
    for (int t = 0; t < K; ++t) {
      int j = ji[(r << 4) + t];
      uint4 v = *(const uint4*)(AbfB + (size_t)j * C + g * 8);
      s0 += bflo(v.x); s1 += bfhi(v.x);
      s2 += bflo(v.y); s3 += bfhi(v.y);
      s4 += bflo(v.z); s5 += bfhi(v.z);
      s6 += bflo(v.w); s7 += bfhi(v.w);
    }
    uint4 o;
    o.x = (u32)f2bf(s0) | ((u32)f2bf(s1) << 16);
    o.y = (u32)f2bf(s2) | ((u32)f2bf(s3) << 16);
    o.z = (u32)f2bf(s4) | ((u32)f2bf(s5) << 16);
    o.w = (u32)f2bf(s6) | ((u32)f2bf(s7) << 16);
    *(uint4*)(&Sl[r][g * 8]) = o;
  }
  __syncthreads();

  // MFMA: wave = col-tile ct (16 cols); 2 row-tiles (rows 0-15, 16-31).
  // A row = lane&15, k-chunk = (lane>>4)*8 ; B col = lane&15, same k-chunk.
  int lane = tid & 63, wave = tid >> 6;  // 8 waves
  int lrow = lane & 15;
  int kgrp = (lane >> 4) * 8;
  int ct = wave;
  f32x4 acc0 = {0.f, 0.f, 0.f, 0.f};
  f32x4 acc1 = {0.f, 0.f, 0.f, 0.f};
  const unsigned short* a0p = Abf + (size_t)(row0 + lrow) * C + kgrp;
  const unsigned short* a1p = Abf + (size_t)(row0 + 16 + lrow) * C + kgrp;
  const unsigned short* wcp = Wcbf + (size_t)(ct * 16 + lrow) * C + kgrp;
  const unsigned short* wgp = Wgbf + (size_t)(ct * 16 + lrow) * C + kgrp;
#pragma unroll
  for (int ks = 0; ks < 4; ++ks) {
    short8_t bC = *(const short8_t*)(wcp + ks * 32);
    short8_t av0 = *(const short8_t*)(a0p + ks * 32);
    short8_t av1 = *(const short8_t*)(a1p + ks * 32);
    acc0 = __builtin_amdgcn_mfma_f32_16x16x32_bf16(av0, bC, acc0, 0, 0, 0);
    acc1 = __builtin_amdgcn_mfma_f32_16x16x32_bf16(av1, bC, acc1, 0, 0, 0);
  }
#pragma unroll
  for (int ks = 0; ks < 4; ++ks) {
    short8_t bG = *(const short8_t*)(wgp + ks * 32);
    short8_t sv0 = *(const short8_t*)(&Sl[lrow][kgrp + ks * 32]);
    short8_t sv1 = *(const short8_t*)(&Sl[16 + lrow][kgrp + ks * 32]);
    acc0 = __builtin_amdgcn_mfma_f32_16x16x32_bf16(sv0, bG, acc0, 0, 0, 0);
    acc1 = __builtin_amdgcn_mfma_f32_16x16x32_bf16(sv1, bG, acc1, 0, 0, 0);
  }

  // stage fragments: D row=(lane>>4)*4+q, col=lane&15 (within 16x16 tile)
  {
    int colw = ct * 16 + lrow;
    int rbase = (lane >> 4) * 4;
#pragma unroll
    for (int q = 0; q < 4; ++q) {
      Pst[rbase + q][colw] = acc0[q];
      Pst[16 + rbase + q][colw] = acc1[q];
    }
  }
  __syncthreads();

  // coalesced epilogue: thread -> (row, 8 cols); float4/uint4 global I/O
  {
    int r = tid >> 4;           // 0..31
    int c8 = (tid & 15) * 8;
    size_t goff = (size_t)(row0 + r) * C + c8;
    float4 av = *(const float4*)&Pst[r][c8];
    float4 aw = *(const float4*)&Pst[r][c8 + 4];
    float4 bcv0 = *(const float4*)&bc[c8];
    float4 bcv1 = *(const float4*)&bc[c8 + 4];
    float4 bgv0 = *(const float4*)&bg[c8];
    float4 bgv1 = *(const float4*)&bg[c8 + 4];
    float4 pv0 = *(const float4*)&Pcur[goff];
    float4 pv1 = *(const float4*)&Pcur[goff + 4];
    float4 o0, o1;
    o0.x = (av.x + (bcv0.x + 16.0f * bgv0.x)) * (1.0f / 17.0f) + pv0.x;
    o0.y = (av.y + (bcv0.y + 16.0f * bgv0.y)) * (1.0f / 17.0f) + pv0.y;
    o0.z = (av.z + (bcv0.z + 16.0f * bgv0.z)) * (1.0f / 17.0f) + pv0.z;
    o0.w = (av.w + (bcv0.w + 16.0f * bgv0.w)) * (1.0f / 17.0f) + pv0.w;
    o1.x = (aw.x + (bcv1.x + 16.0f * bgv1.x)) * (1.0f / 17.0f) + pv1.x;
    o1.y = (aw.y + (bcv1.y + 16.0f * bgv1.y)) * (1.0f / 17.0f) + pv1.y;
    o1.z = (aw.z + (bcv1.z + 16.0f * bgv1.z)) * (1.0f / 17.0f) + pv1.z;
    o1.w = (aw.w + (bcv1.w + 16.0f * bgv1.w)) * (1.0f / 17.0f) + pv1.w;
    *(float4*)&Pnxt[goff] = o0;
    *(float4*)&Pnxt[goff + 4] = o1;
    if (AbfN) {
      uint4 ob;
      ob.x = (u32)f2bf(leaky(o0.x)) | ((u32)f2bf(leaky(o0.y)) << 16);
      ob.y = (u32)f2bf(leaky(o0.z)) | ((u32)f2bf(leaky(o0.w)) << 16);
      ob.z = (u32)f2bf(leaky(o1.x)) | ((u32)f2bf(leaky(o1.y)) << 16);
      ob.w = (u32)f2bf(leaky(o1.z)) | ((u32)f2bf(leaky(o1.w)) << 16);
      *(uint4*)(AbfN + goff) = ob;
    }
  }
}

extern "C" void kernel_launch(void* const* d_in, const int* in_sizes, int n_in,
                              void* d_out, int out_size, void* d_ws, size_t ws_size,
                              hipStream_t stream) {
  const float* xyz = (const float*)d_in[0];
  const float* pts = (const float*)d_in[1];
  const float* Wc = (const float*)d_in[5];
  const float* bc = (const float*)d_in[6];
  const float* Wg = (const float*)d_in[7];
  const float* bg = (const float*)d_in[8];

  const size_t PE = (size_t)B * N * C;            // 2097152 elements
  const size_t idxB = (size_t)B * N * K * 4;      // 1 MB
  const size_t WbfB = (size_t)2 * NB * C * C * 2; // 192 KB
  char* ws = (char*)d_ws;
  float* Pa            = (float*)ws;                                  // 8 MB
  int* idx             = (int*)(ws + PE * 4);                         // 1 MB
  unsigned short* Abf0 = (unsigned short*)(ws + PE * 4 + idxB);       // 4 MB
  unsigned short* Wbf  = (unsigned short*)(ws + PE * 4 + idxB + PE * 2);
  unsigned short* Abf1 = (unsigned short*)(ws + PE * 4 + idxB + PE * 2 + WbfB);
  unsigned short* Wcbf = Wbf;
  unsigned short* Wgbf = Wbf + (size_t)NB * C * C;
  const size_t need = PE * 4 + idxB + PE * 2 + WbfB + PE * 2;  // 17.2 MB
  const bool fusedAbf = (ws_size >= need);

  hipLaunchKernelGGL(cvtW_kernel, dim3((2 * NB * C * C) / 256), dim3(256), 0, stream,
                     Wc, Wg, Wbf);
  hipLaunchKernelGGL(cvtA_kernel, dim3(1024), dim3(256), 0, stream, pts, Abf0);
  hipLaunchKernelGGL(knn_kernel, dim3(2048), dim3(512), 0, stream, xyz, idx);

  // ping-pong: pts (read-only) -> d_out -> Pa -> d_out
  const float* cur = pts;
  float* nxt = (float*)d_out;
  unsigned short* AbfCur = Abf0;
  unsigned short* AbfNxt = fusedAbf ? Abf1 : Abf0;
  for (int i = 0; i < NB; ++i) {
    if (!fusedAbf && i > 0) {
      hipLaunchKernelGGL(cvtA_kernel, dim3(1024), dim3(256), 0, stream, cur, Abf0);
      AbfCur = Abf0;
    }
    unsigned short* an = (fusedAbf && i < NB - 1) ? AbfNxt : (unsigned short*)nullptr;
    hipLaunchKernelGGL(fused_kernel, dim3((B * N) / RB), dim3(512), 0, stream,
                       cur, AbfCur, idx, Wcbf + (size_t)i * C * C, Wgbf + (size_t)i * C * C,
                       bc + (size_t)i * C, bg + (size_t)i * C, nxt, an);
    cur = nxt;
    nxt = (i == 0) ? Pa : (float*)d_out;
    if (fusedAbf) { unsigned short* ta = AbfCur; AbfCur = AbfNxt; AbfNxt = ta; }
  }
}

// Round 19
// 98.085 us; speedup vs baseline: 1.1335x; 1.0256x over previous
//
#include <hip/hip_runtime.h>
#include <math.h>

#define B  4
#define N  4096
#define C  128
#define K  16
#define NB 3
#define RB 32  // fused: rows per block

typedef unsigned int u32;
typedef unsigned long long u64;
typedef __attribute__((ext_vector_type(8))) short short8_t;
typedef __attribute__((ext_vector_type(4))) float f32x4;

__device__ __forceinline__ float leaky(float x) {
  return x >= 0.f ? x : 0.01f * x;
}
__device__ __forceinline__ unsigned short f2bf(float f) {
  u32 x = __float_as_uint(f);
  return (unsigned short)((x + 0x7FFFu + ((x >> 16) & 1u)) >> 16);  // RNE
}
__device__ __forceinline__ float bflo(u32 u) { return __uint_as_float(u << 16); }
__device__ __forceinline__ float bfhi(u32 u) { return __uint_as_float(u & 0xFFFF0000u); }
__device__ __forceinline__ u32 umaxu(u32 a, u32 b) { return a > b ? a : b; }

// XCD-pair swizzle: bidx=(q*8+x) -> batch b=x>>1, row-group rgrp=2q+(x&1).
__device__ __forceinline__ void swz_batch(int bidx, int* b, int* rgrp) {
  int q = bidx >> 3, x = bidx & 7;
  *b = x >> 1;
  *rgrp = (q << 1) | (x & 1);
}

// 64-lane max reduce, pure VALU via DPP. Result valid in lane 63.
__device__ __forceinline__ u32 dpp_max64(u32 v) {
  v = umaxu(v, (u32)__builtin_amdgcn_update_dpp(0, (int)v, 0x111, 0xf, 0xf, false));
  v = umaxu(v, (u32)__builtin_amdgcn_update_dpp(0, (int)v, 0x112, 0xf, 0xf, false));
  v = umaxu(v, (u32)__builtin_amdgcn_update_dpp(0, (int)v, 0x114, 0xf, 0xf, false));
  v = umaxu(v, (u32)__builtin_amdgcn_update_dpp(0, (int)v, 0x118, 0xf, 0xf, false));
  v = umaxu(v, (u32)__builtin_amdgcn_update_dpp(0, (int)v, 0x142, 0xa, 0xf, false));
  v = umaxu(v, (u32)__builtin_amdgcn_update_dpp(0, (int)v, 0x143, 0xc, 0xf, false));
  return v;
}

// exact monotone-encoded squared distance (reference op order, no contraction)
__device__ __forceinline__ u32 encdist(float xi, float yi, float zi, float sqi,
                                       float4 pj) {
  float dt = __fadd_rn(__fmul_rn(xi, pj.x), __fmul_rn(yi, pj.y));
  dt = __fadd_rn(dt, __fmul_rn(zi, pj.z));
  float dd = __fsub_rn(__fadd_rn(sqi, pj.w), __fmul_rn(2.0f, dt));
  u32 bits = __float_as_uint(dd);
  return bits ^ ((u32)(((int)bits) >> 31) | 0x80000000u);
}

// cheap approximate distance (fma contraction allowed), clamped to >= 0.
// Used ONLY for the tau threshold / survivor predicate (with 1-quantum slack);
// exact encdist is recomputed for all survivors.
__device__ __forceinline__ float apxdist(float xi, float yi, float zi, float sqi,
                                         float4 pj) {
  float dd = (sqi + pj.w) - 2.0f * (xi * pj.x + (yi * pj.y + zi * pj.z));
  return fmaxf(dd, 0.0f);
}

// ---- KNN (faithful: k+1 LARGEST sq-dists, drop first) ----
// Round-16 version verbatim (best measured: 47.7us, VGPR 52; FROZEN — r12/13/
// 14/17 structural variants all regressed). 2048 blocks x 512 threads.
__global__ __launch_bounds__(512) void knn_kernel(const float* __restrict__ xyz,
                                                  int* __restrict__ idxOut) {
  __shared__ float4 p[N];       // 64 KB
  __shared__ u64 surv[8][64];   // 4 KB survivor buffer, per wave
  int bidx = blockIdx.x;
  int b = bidx >> 9;            // 512 blocks per batch
  int row0 = (bidx & 511) << 3; // 8 rows per block
  const float* src = xyz + b * N * 3;
  int tid = threadIdx.x;

  for (int e = tid; e < N; e += 512) {
    float x = src[3 * e], y = src[3 * e + 1], z = src[3 * e + 2];
    // sq = (x*x + y*y) + z*z, exact f32 rounding, no FMA contraction
    float sq = __fadd_rn(__fadd_rn(__fmul_rn(x, x), __fmul_rn(y, y)), __fmul_rn(z, z));
    p[e] = make_float4(x, y, z, sq);
  }
  __syncthreads();

  int lane = tid & 63;
  int wave = tid >> 6;   // 0..7 = local row
  int i = row0 + wave;   // query point within batch

  float4 pi = p[i];
  float xi = pi.x, yi = pi.y, zi = pi.z, sqi = pi.w;

  // Phase A: approx distances; pack hi16; float running max
  u32 denc16[32];
  float fmx = 0.0f;
#pragma unroll
  for (int t2 = 0; t2 < 32; ++t2) {
    int t0 = t2 * 2, t1 = t0 + 1;
    float4 pj0 = p[lane + (t0 << 6)];
    float4 pj1 = p[lane + (t1 << 6)];
    float d0 = apxdist(xi, yi, zi, sqi, pj0);
    float d1 = apxdist(xi, yi, zi, sqi, pj1);
    fmx = fmaxf(fmx, fmaxf(d0, d1));
    denc16[t2] = (__float_as_uint(d0) >> 16) | (__float_as_uint(d1) & 0xFFFF0000u);
  }

  // Phase B: sort the 64 lane-max values (u32 bits, all >= +0) descending
  u32 sv = __float_as_uint(fmx);
#pragma unroll
  for (int k2 = 2; k2 <= 64; k2 <<= 1) {
#pragma unroll
    for (int jj = k2 >> 1; jj > 0; jj >>= 1) {
      u32 ov = (u32)__shfl_xor((int)sv, jj, 64);
      bool keepMax = ((lane & jj) == 0) == ((lane & k2) == 0);
      sv = (keepMax == (ov > sv)) ? ov : sv;
    }
  }
  u32 th = ((u32)__shfl((int)sv, 16, 64)) >> 16;
  u32 tau16 = (th > 0u) ? (th - 1u) : 0u;  // 1-quantum slack (superset)

  // Phase C: ballot-compact candidates with hi16(approx) >= tau16; exact keys
  int total = 0;
#pragma unroll
  for (int t = 0; t < 64; ++t) {
    u32 h = (t & 1) ? (denc16[t >> 1] >> 16) : (denc16[t >> 1] & 0xFFFFu);
    bool pred = (h >= tau16);
    u64 bal = __ballot(pred);
    if (bal != 0ull) {  // wave-uniform skip of empty slots
      int pos = total + (int)__builtin_amdgcn_mbcnt_hi(
                            (u32)(bal >> 32),
                            __builtin_amdgcn_mbcnt_lo((u32)bal, 0u));
      if (pred && pos < 64) {
        u32 enc = encdist(xi, yi, zi, sqi, p[lane + (t << 6)]);  // exact
        surv[wave][pos] = ((u64)enc << 32) | (u32)(4095 - (lane + (t << 6)));
      }
      total += (int)__popcll(bal);
    }
  }

  if (total <= 64) {
    // Phase D: sort survivors descending (zeros pad to the end), emit 1..16.
    u64 sk = (lane < total) ? surv[wave][lane] : 0ull;
#pragma unroll
    for (int k2 = 2; k2 <= 64; k2 <<= 1) {
#pragma unroll
      for (int jj = k2 >> 1; jj > 0; jj >>= 1) {
        u64 ok = __shfl_xor(sk, jj, 64);
        bool keepMax = ((lane & jj) == 0) == ((lane & k2) == 0);
        sk = (keepMax == (ok > sk)) ? ok : sk;
      }
    }
    if (lane >= 1 && lane < 17) {
      idxOut[((long long)(b * N + i)) * K + lane - 1] = 4095 - (int)(u32)sk;
    }
  } else {
    // Fallback (degenerate ties; never on this input): exact iterative
    // extraction; recomputes its own exact argmax first.
    u32 cmax = 0u; u32 ct = 0u;
#pragma unroll
    for (int t = 0; t < 64; ++t) {
      u32 enc = encdist(xi, yi, zi, sqi, p[lane + (t << 6)]);
      if (enc > cmax) { cmax = enc; ct = (u32)t; }
    }
    u64 elim = 0ull;
    for (int r = 0; r < 17; ++r) {
      u32 wmax = dpp_max64(cmax);
      u32 s_wmax = (u32)__builtin_amdgcn_readlane((int)wmax, 63);
      u64 mask = __ballot(cmax == s_wmax);
      int s_wj;
      if (__popcll(mask) == 1) {
        int l = (int)(__ffsll((long long)mask) - 1);
        int myj = lane + ((int)ct << 6);
        s_wj = __builtin_amdgcn_readlane(myj, l);
      } else {
        u32 jv = (cmax == s_wmax) ? (u32)(lane + ((int)ct << 6)) : 0xFFFFFFFFu;
#pragma unroll
        for (int off = 1; off < 64; off <<= 1) {
          u32 oj = (u32)__shfl_xor((int)jv, off, 64);
          jv = oj < jv ? oj : jv;
        }
        s_wj = (int)__builtin_amdgcn_readfirstlane((int)jv);
      }
      if (r > 0 && lane == 0)
        idxOut[((long long)(b * N + i)) * K + (r - 1)] = s_wj;
      if (r == 16) break;
      if (lane == (s_wj & 63)) {
        elim |= 1ull << (s_wj >> 6);
        cmax = 0u; ct = 0u;
        for (int t = 0; t < 64; ++t) {
          if (elim & (1ull << t)) continue;
          u32 enc = encdist(xi, yi, zi, sqi, p[lane + (t << 6)]);
          if (enc > cmax) { cmax = enc; ct = (u32)t; }
        }
      }
    }
  }
}

// ---- Abf = bf16(leaky(P)) : XCD-pair swizzled (1024 blocks x 256) ----
__global__ __launch_bounds__(256) void cvtA_kernel(const float* __restrict__ P,
                                                   unsigned short* __restrict__ Abf) {
  int b, rgrp;
  swz_batch(blockIdx.x, &b, &rgrp);
  int tid = threadIdx.x;
  size_t off = ((size_t)b * N + rgrp * 16 + (tid >> 4)) * C + (tid & 15) * 8;
  const float4* p4 = (const float4*)(P + off);
  float4 a = p4[0], c = p4[1];
  unsigned short u0 = f2bf(leaky(a.x)), u1 = f2bf(leaky(a.y));
  unsigned short u2 = f2bf(leaky(a.z)), u3 = f2bf(leaky(a.w));
  unsigned short u4 = f2bf(leaky(c.x)), u5 = f2bf(leaky(c.y));
  unsigned short u6 = f2bf(leaky(c.z)), u7 = f2bf(leaky(c.w));
  uint4 o;
  o.x = (u32)u0 | ((u32)u1 << 16);
  o.y = (u32)u2 | ((u32)u3 << 16);
  o.z = (u32)u4 | ((u32)u5 << 16);
  o.w = (u32)u6 | ((u32)u7 << 16);
  *(uint4*)(Abf + off) = o;
}

// ---- W (f32) -> bf16, all 3 blocks at once ----
__global__ __launch_bounds__(256) void cvtW_kernel(const float* __restrict__ Wc,
                                                   const float* __restrict__ Wg,
                                                   unsigned short* __restrict__ Wbf) {
  int e = blockIdx.x * 256 + threadIdx.x;  // 0..98303
  if (e < NB * C * C) Wbf[e] = f2bf(Wc[e]);
  else Wbf[e] = f2bf(Wg[e - NB * C * C]);
}

// ---- fused per-block-iter: gather-sum (bf16) + dual MFMA matmul + epilogue
// 512 blocks x 512 threads (8 waves), XCD-pair swizzled. Block = RB=32 rows.
// Wave w = col-tile w (16 cols) x 2 row-tiles. LDS-staged coalesced epilogue.
// r19: weight B-operands prefetched BEFORE the gather phase (their L2 latency
// overlaps the gather's 16 independent loads instead of serializing after the
// barrier); Pcur epilogue read issued before the staging barrier.
__global__ __launch_bounds__(512) void fused_kernel(
    const float* __restrict__ Pcur, const unsigned short* __restrict__ Abf,
    const int* __restrict__ idx,
    const unsigned short* __restrict__ Wcbf, const unsigned short* __restrict__ Wgbf,
    const float* __restrict__ bc, const float* __restrict__ bg,
    float* __restrict__ Pnxt, unsigned short* __restrict__ AbfN) {
  __shared__ int ji[RB * K];              // 2 KB
  __shared__ unsigned short Sl[RB][136];  // 8.7 KB (+8 pad)
  __shared__ float Pst[RB][128];          // 16 KB epilogue staging
  int bb, rgrp;
  swz_batch(blockIdx.x, &bb, &rgrp);      // 512 blocks: rgrp 0..127
  int row0 = bb * N + rgrp * RB;          // global row
  int tid = threadIdx.x;
  ji[tid] = idx[row0 * K + tid];          // RB*K = 512 = blockDim
  __syncthreads();

  // batch base for neighbor indices (idx entries are within-batch!)
  const unsigned short* AbfB = Abf + ((size_t)bb << 12) * C;

  // prefetch weight B-operands now: 8 x 16B/lane in flight across the gather
  int lane = tid & 63, wave = tid >> 6;  // 8 waves
  int lrow = lane & 15;
  int kgrp = (lane >> 4) * 8;
  int ct = wave;
  const unsigned short* wcp = Wcbf + (size_t)(ct * 16 + lrow) * C + kgrp;
  const unsigned short* wgp = Wgbf + (size_t)(ct * 16 + lrow) * C + kgrp;
  short8_t bCw[4], bGw[4];
#pragma unroll
  for (int ks = 0; ks < 4; ++ks) {
    bCw[ks] = *(const short8_t*)(wcp + ks * 32);
    bGw[ks] = *(const short8_t*)(wgp + ks * 32);
  }

  // gather: thread (r,g) sums 8 cols [g*8, g*8+8) of row r over 16 neighbors
  {
    int r = tid >> 4, g = tid & 15;  // r 0..31
    float s0 = 0.f, s1 = 0.f, s2 = 0.f, s3 = 0.f, s4 = 0.f, s5 = 0.f, s6 = 0.f, s7 = 0.f;
#pragma unroll
    for (int t = 0; t < K; ++t) {
      int j = ji[(r << 4) + t];
      uint4 v = *(const uint4*)(AbfB + (size_t)j * C + g * 8);
      s0 += bflo(v.x); s1 += bfhi(v.x);
      s2 += bflo(v.y); s3 += bfhi(v.y);
      s4 += bflo(v.z); s5 += bfhi(v.z);
      s6 += bflo(v.w); s7 += bfhi(v.w);
    }
    uint4 o;
    o.x = (u32)f2bf(s0) | ((u32)f2bf(s1) << 16);
    o.y = (u32)f2bf(s2) | ((u32)f2bf(s3) << 16);
    o.z = (u32)f2bf(s4) | ((u32)f2bf(s5) << 16);
    o.w = (u32)f2bf(s6) | ((u32)f2bf(s7) << 16);
    *(uint4*)(&Sl[r][g * 8]) = o;
  }
  __syncthreads();

  // MFMA: wave = col-tile ct (16 cols); 2 row-tiles (rows 0-15, 16-31).
  // A row = lane&15, k-chunk = (lane>>4)*8 ; B col = lane&15, same k-chunk.
  f32x4 acc0 = {0.f, 0.f, 0.f, 0.f};
  f32x4 acc1 = {0.f, 0.f, 0.f, 0.f};
  const unsigned short* a0p = Abf + (size_t)(row0 + lrow) * C + kgrp;
  const unsigned short* a1p = Abf + (size_t)(row0 + 16 + lrow) * C + kgrp;
#pragma unroll
  for (int ks = 0; ks < 4; ++ks) {
    short8_t av0 = *(const short8_t*)(a0p + ks * 32);
    short8_t av1 = *(const short8_t*)(a1p + ks * 32);
    acc0 = __builtin_amdgcn_mfma_f32_16x16x32_bf16(av0, bCw[ks], acc0, 0, 0, 0);
    acc1 = __builtin_amdgcn_mfma_f32_16x16x32_bf16(av1, bCw[ks], acc1, 0, 0, 0);
  }
#pragma unroll
  for (int ks = 0; ks < 4; ++ks) {
    short8_t sv0 = *(const short8_t*)(&Sl[lrow][kgrp + ks * 32]);
    short8_t sv1 = *(const short8_t*)(&Sl[16 + lrow][kgrp + ks * 32]);
    acc0 = __builtin_amdgcn_mfma_f32_16x16x32_bf16(sv0, bGw[ks], acc0, 0, 0, 0);
    acc1 = __builtin_amdgcn_mfma_f32_16x16x32_bf16(sv1, bGw[ks], acc1, 0, 0, 0);
  }

  // issue the epilogue's Pcur read early (hides L2/L3 latency under the
  // staging barrier + Pst reads)
  int er = tid >> 4;           // 0..31
  int ec8 = (tid & 15) * 8;
  size_t goff = (size_t)(row0 + er) * C + ec8;
  float4 pv0 = *(const float4*)&Pcur[goff];
  float4 pv1 = *(const float4*)&Pcur[goff + 4];

  // stage fragments: D row=(lane>>4)*4+q, col=lane&15 (within 16x16 tile)
  {
    int colw = ct * 16 + lrow;
    int rbase = (lane >> 4) * 4;
#pragma unroll
    for (int q = 0; q < 4; ++q) {
      Pst[rbase + q][colw] = acc0[q];
      Pst[16 + rbase + q][colw] = acc1[q];
    }
  }
  __syncthreads();

  // coalesced epilogue: thread -> (row, 8 cols); float4/uint4 global I/O
  {
    float4 av = *(const float4*)&Pst[er][ec8];
    float4 aw = *(const float4*)&Pst[er][ec8 + 4];
    float4 bcv0 = *(const float4*)&bc[ec8];
    float4 bcv1 = *(const float4*)&bc[ec8 + 4];
    float4 bgv0 = *(const float4*)&bg[ec8];
    float4 bgv1 = *(const float4*)&bg[ec8 + 4];
    float4 o0, o1;
    o0.x = (av.x + (bcv0.x + 16.0f * bgv0.x)) * (1.0f / 17.0f) + pv0.x;
    o0.y = (av.y + (bcv0.y + 16.0f * bgv0.y)) * (1.0f / 17.0f) + pv0.y;
    o0.z = (av.z + (bcv0.z + 16.0f * bgv0.z)) * (1.0f / 17.0f) + pv0.z;
    o0.w = (av.w + (bcv0.w + 16.0f * bgv0.w)) * (1.0f / 17.0f) + pv0.w;
    o1.x = (aw.x + (bcv1.x + 16.0f * bgv1.x)) * (1.0f / 17.0f) + pv1.x;
    o1.y = (aw.y + (bcv1.y + 16.0f * bgv1.y)) * (1.0f / 17.0f) + pv1.y;
    o1.z = (aw.z + (bcv1.z + 16.0f * bgv1.z)) * (1.0f / 17.0f) + pv1.z;
    o1.w = (aw.w + (bcv1.w + 16.0f * bgv1.w)) * (1.0f / 17.0f) + pv1.w;
    *(float4*)&Pnxt[goff] = o0;
    *(float4*)&Pnxt[goff + 4] = o1;
    if (AbfN) {
      uint4 ob;
      ob.x = (u32)f2bf(leaky(o0.x)) | ((u32)f2bf(leaky(o0.y)) << 16);
      ob.y = (u32)f2bf(leaky(o0.z)) | ((u32)f2bf(leaky(o0.w)) << 16);
      ob.z = (u32)f2bf(leaky(o1.x)) | ((u32)f2bf(leaky(o1.y)) << 16);
      ob.w = (u32)f2bf(leaky(o1.z)) | ((u32)f2bf(leaky(o1.w)) << 16);
      *(uint4*)(AbfN + goff) = ob;
    }
  }
}

extern "C" void kernel_launch(void* const* d_in, const int* in_sizes, int n_in,
                              void* d_out, int out_size, void* d_ws, size_t ws_size,
                              hipStream_t stream) {
  const float* xyz = (const float*)d_in[0];
  const float* pts = (const float*)d_in[1];
  const float* Wc = (const float*)d_in[5];
  const float* bc = (const float*)d_in[6];
  const float* Wg = (const float*)d_in[7];
  const float* bg = (const float*)d_in[8];

  const size_t PE = (size_t)B * N * C;            // 2097152 elements
  const size_t idxB = (size_t)B * N * K * 4;      // 1 MB
  const size_t WbfB = (size_t)2 * NB * C * C * 2; // 192 KB
  char* ws = (char*)d_ws;
  float* Pa            = (float*)ws;                                  // 8 MB
  int* idx             = (int*)(ws + PE * 4);                         // 1 MB
  unsigned short* Abf0 = (unsigned short*)(ws + PE * 4 + idxB);       // 4 MB
  unsigned short* Wbf  = (unsigned short*)(ws + PE * 4 + idxB + PE * 2);
  unsigned short* Abf1 = (unsigned short*)(ws + PE * 4 + idxB + PE * 2 + WbfB);
  unsigned short* Wcbf = Wbf;
  unsigned short* Wgbf = Wbf + (size_t)NB * C * C;
  const size_t need = PE * 4 + idxB + PE * 2 + WbfB + PE * 2;  // 17.2 MB
  const bool fusedAbf = (ws_size >= need);

  hipLaunchKernelGGL(cvtW_kernel, dim3((2 * NB * C * C) / 256), dim3(256), 0, stream,
                     Wc, Wg, Wbf);
  hipLaunchKernelGGL(cvtA_kernel, dim3(1024), dim3(256), 0, stream, pts, Abf0);
  hipLaunchKernelGGL(knn_kernel, dim3(2048), dim3(512), 0, stream, xyz, idx);

  // ping-pong: pts (read-only) -> d_out -> Pa -> d_out
  const float* cur = pts;
  float* nxt = (float*)d_out;
  unsigned short* AbfCur = Abf0;
  unsigned short* AbfNxt = fusedAbf ? Abf1 : Abf0;
  for (int i = 0; i < NB; ++i) {
    if (!fusedAbf && i > 0) {
      hipLaunchKernelGGL(cvtA_kernel, dim3(1024), dim3(256), 0, stream, cur, Abf0);
      AbfCur = Abf0;
    }
    unsigned short* an = (fusedAbf && i < NB - 1) ? AbfNxt : (unsigned short*)nullptr;
    hipLaunchKernelGGL(fused_kernel, dim3((B * N) / RB), dim3(512), 0, stream,
                       cur, AbfCur, idx, Wcbf + (size_t)i * C * C, Wgbf + (size_t)i * C * C,
                       bc + (size_t)i * C, bg + (size_t)i * C, nxt, an);
    cur = nxt;
    nxt = (i == 0) ? Pa : (float*)d_out;
    if (fusedAbf) { unsigned short* ta = AbfCur; AbfCur = AbfNxt; AbfNxt = ta; }
  }
}

// Round 20
// 93.571 us; speedup vs baseline: 1.1881x; 1.0482x over previous
//
#include <hip/hip_runtime.h>
#include <math.h>

#define B  4
#define N  4096
#define C  128
#define K  16
#define NB 3
#define RB 64  // fused: rows per block (r20: 64 halves weight re-read traffic)

typedef unsigned int u32;
typedef unsigned long long u64;
typedef __attribute__((ext_vector_type(8))) short short8_t;
typedef __attribute__((ext_vector_type(4))) float f32x4;

__device__ __forceinline__ float leaky(float x) {
  return x >= 0.f ? x : 0.01f * x;
}
__device__ __forceinline__ unsigned short f2bf(float f) {
  u32 x = __float_as_uint(f);
  return (unsigned short)((x + 0x7FFFu + ((x >> 16) & 1u)) >> 16);  // RNE
}
__device__ __forceinline__ float bflo(u32 u) { return __uint_as_float(u << 16); }
__device__ __forceinline__ float bfhi(u32 u) { return __uint_as_float(u & 0xFFFF0000u); }
__device__ __forceinline__ u32 umaxu(u32 a, u32 b) { return a > b ? a : b; }

// XCD-pair swizzle: bidx=(q*8+x) -> batch b=x>>1, row-group rgrp=2q+(x&1).
__device__ __forceinline__ void swz_batch(int bidx, int* b, int* rgrp) {
  int q = bidx >> 3, x = bidx & 7;
  *b = x >> 1;
  *rgrp = (q << 1) | (x & 1);
}

// 64-lane max reduce, pure VALU via DPP. Result valid in lane 63.
__device__ __forceinline__ u32 dpp_max64(u32 v) {
  v = umaxu(v, (u32)__builtin_amdgcn_update_dpp(0, (int)v, 0x111, 0xf, 0xf, false));
  v = umaxu(v, (u32)__builtin_amdgcn_update_dpp(0, (int)v, 0x112, 0xf, 0xf, false));
  v = umaxu(v, (u32)__builtin_amdgcn_update_dpp(0, (int)v, 0x114, 0xf, 0xf, false));
  v = umaxu(v, (u32)__builtin_amdgcn_update_dpp(0, (int)v, 0x118, 0xf, 0xf, false));
  v = umaxu(v, (u32)__builtin_amdgcn_update_dpp(0, (int)v, 0x142, 0xa, 0xf, false));
  v = umaxu(v, (u32)__builtin_amdgcn_update_dpp(0, (int)v, 0x143, 0xc, 0xf, false));
  return v;
}

// exact monotone-encoded squared distance (reference op order, no contraction)
__device__ __forceinline__ u32 encdist(float xi, float yi, float zi, float sqi,
                                       float4 pj) {
  float dt = __fadd_rn(__fmul_rn(xi, pj.x), __fmul_rn(yi, pj.y));
  dt = __fadd_rn(dt, __fmul_rn(zi, pj.z));
  float dd = __fsub_rn(__fadd_rn(sqi, pj.w), __fmul_rn(2.0f, dt));
  u32 bits = __float_as_uint(dd);
  return bits ^ ((u32)(((int)bits) >> 31) | 0x80000000u);
}

// cheap approximate distance (fma contraction allowed), clamped to >= 0.
// Used ONLY for the tau threshold / survivor predicate (with 1-quantum slack);
// exact encdist is recomputed for all survivors.
__device__ __forceinline__ float apxdist(float xi, float yi, float zi, float sqi,
                                         float4 pj) {
  float dd = (sqi + pj.w) - 2.0f * (xi * pj.x + (yi * pj.y + zi * pj.z));
  return fmaxf(dd, 0.0f);
}

// ---- KNN (faithful: k+1 LARGEST sq-dists, drop first) ----
// Round-16 version verbatim (best measured: 47.7us, VGPR 52; FROZEN — r12/13/
// 14/17 structural variants all regressed). 2048 blocks x 512 threads.
__global__ __launch_bounds__(512) void knn_kernel(const float* __restrict__ xyz,
                                                  int* __restrict__ idxOut) {
  __shared__ float4 p[N];       // 64 KB
  __shared__ u64 surv[8][64];   // 4 KB survivor buffer, per wave
  int bidx = blockIdx.x;
  int b = bidx >> 9;            // 512 blocks per batch
  int row0 = (bidx & 511) << 3; // 8 rows per block
  const float* src = xyz + b * N * 3;
  int tid = threadIdx.x;

  for (int e = tid; e < N; e += 512) {
    float x = src[3 * e], y = src[3 * e + 1], z = src[3 * e + 2];
    // sq = (x*x + y*y) + z*z, exact f32 rounding, no FMA contraction
    float sq = __fadd_rn(__fadd_rn(__fmul_rn(x, x), __fmul_rn(y, y)), __fmul_rn(z, z));
    p[e] = make_float4(x, y, z, sq);
  }
  __syncthreads();

  int lane = tid & 63;
  int wave = tid >> 6;   // 0..7 = local row
  int i = row0 + wave;   // query point within batch

  float4 pi = p[i];
  float xi = pi.x, yi = pi.y, zi = pi.z, sqi = pi.w;

  // Phase A: approx distances; pack hi16; float running max
  u32 denc16[32];
  float fmx = 0.0f;
#pragma unroll
  for (int t2 = 0; t2 < 32; ++t2) {
    int t0 = t2 * 2, t1 = t0 + 1;
    float4 pj0 = p[lane + (t0 << 6)];
    float4 pj1 = p[lane + (t1 << 6)];
    float d0 = apxdist(xi, yi, zi, sqi, pj0);
    float d1 = apxdist(xi, yi, zi, sqi, pj1);
    fmx = fmaxf(fmx, fmaxf(d0, d1));
    denc16[t2] = (__float_as_uint(d0) >> 16) | (__float_as_uint(d1) & 0xFFFF0000u);
  }

  // Phase B: sort the 64 lane-max values (u32 bits, all >= +0) descending
  u32 sv = __float_as_uint(fmx);
#pragma unroll
  for (int k2 = 2; k2 <= 64; k2 <<= 1) {
#pragma unroll
    for (int jj = k2 >> 1; jj > 0; jj >>= 1) {
      u32 ov = (u32)__shfl_xor((int)sv, jj, 64);
      bool keepMax = ((lane & jj) == 0) == ((lane & k2) == 0);
      sv = (keepMax == (ov > sv)) ? ov : sv;
    }
  }
  u32 th = ((u32)__shfl((int)sv, 16, 64)) >> 16;
  u32 tau16 = (th > 0u) ? (th - 1u) : 0u;  // 1-quantum slack (superset)

  // Phase C: ballot-compact candidates with hi16(approx) >= tau16; exact keys
  int total = 0;
#pragma unroll
  for (int t = 0; t < 64; ++t) {
    u32 h = (t & 1) ? (denc16[t >> 1] >> 16) : (denc16[t >> 1] & 0xFFFFu);
    bool pred = (h >= tau16);
    u64 bal = __ballot(pred);
    if (bal != 0ull) {  // wave-uniform skip of empty slots
      int pos = total + (int)__builtin_amdgcn_mbcnt_hi(
                            (u32)(bal >> 32),
                            __builtin_amdgcn_mbcnt_lo((u32)bal, 0u));
      if (pred && pos < 64) {
        u32 enc = encdist(xi, yi, zi, sqi, p[lane + (t << 6)]);  // exact
        surv[wave][pos] = ((u64)enc << 32) | (u32)(4095 - (lane + (t << 6)));
      }
      total += (int)__popcll(bal);
    }
  }

  if (total <= 64) {
    // Phase D: sort survivors descending (zeros pad to the end), emit 1..16.
    u64 sk = (lane < total) ? surv[wave][lane] : 0ull;
#pragma unroll
    for (int k2 = 2; k2 <= 64; k2 <<= 1) {
#pragma unroll
      for (int jj = k2 >> 1; jj > 0; jj >>= 1) {
        u64 ok = __shfl_xor(sk, jj, 64);
        bool keepMax = ((lane & jj) == 0) == ((lane & k2) == 0);
        sk = (keepMax == (ok > sk)) ? ok : sk;
      }
    }
    if (lane >= 1 && lane < 17) {
      idxOut[((long long)(b * N + i)) * K + lane - 1] = 4095 - (int)(u32)sk;
    }
  } else {
    // Fallback (degenerate ties; never on this input): exact iterative
    // extraction; recomputes its own exact argmax first.
    u32 cmax = 0u; u32 ct = 0u;
#pragma unroll
    for (int t = 0; t < 64; ++t) {
      u32 enc = encdist(xi, yi, zi, sqi, p[lane + (t << 6)]);
      if (enc > cmax) { cmax = enc; ct = (u32)t; }
    }
    u64 elim = 0ull;
    for (int r = 0; r < 17; ++r) {
      u32 wmax = dpp_max64(cmax);
      u32 s_wmax = (u32)__builtin_amdgcn_readlane((int)wmax, 63);
      u64 mask = __ballot(cmax == s_wmax);
      int s_wj;
      if (__popcll(mask) == 1) {
        int l = (int)(__ffsll((long long)mask) - 1);
        int myj = lane + ((int)ct << 6);
        s_wj = __builtin_amdgcn_readlane(myj, l);
      } else {
        u32 jv = (cmax == s_wmax) ? (u32)(lane + ((int)ct << 6)) : 0xFFFFFFFFu;
#pragma unroll
        for (int off = 1; off < 64; off <<= 1) {
          u32 oj = (u32)__shfl_xor((int)jv, off, 64);
          jv = oj < jv ? oj : jv;
        }
        s_wj = (int)__builtin_amdgcn_readfirstlane((int)jv);
      }
      if (r > 0 && lane == 0)
        idxOut[((long long)(b * N + i)) * K + (r - 1)] = s_wj;
      if (r == 16) break;
      if (lane == (s_wj & 63)) {
        elim |= 1ull << (s_wj >> 6);
        cmax = 0u; ct = 0u;
        for (int t = 0; t < 64; ++t) {
          if (elim & (1ull << t)) continue;
          u32 enc = encdist(xi, yi, zi, sqi, p[lane + (t << 6)]);
          if (enc > cmax) { cmax = enc; ct = (u32)t; }
        }
      }
    }
  }
}

// ---- Abf = bf16(leaky(P)) : XCD-pair swizzled (1024 blocks x 256) ----
__global__ __launch_bounds__(256) void cvtA_kernel(const float* __restrict__ P,
                                                   unsigned short* __restrict__ Abf) {
  int b, rgrp;
  swz_batch(blockIdx.x, &b, &rgrp);
  int tid = threadIdx.x;
  size_t off = ((size_t)b * N + rgrp * 16 + (tid >> 4)) * C + (tid & 15) * 8;
  const float4* p4 = (const float4*)(P + off);
  float4 a = p4[0], c = p4[1];
  unsigned short u0 = f2bf(leaky(a.x)), u1 = f2bf(leaky(a.y));
  unsigned short u2 = f2bf(leaky(a.z)), u3 = f2bf(leaky(a.w));
  unsigned short u4 = f2bf(leaky(c.x)), u5 = f2bf(leaky(c.y));
  unsigned short u6 = f2bf(leaky(c.z)), u7 = f2bf(leaky(c.w));
  uint4 o;
  o.x = (u32)u0 | ((u32)u1 << 16);
  o.y = (u32)u2 | ((u32)u3 << 16);
  o.z = (u32)u4 | ((u32)u5 << 16);
  o.w = (u32)u6 | ((u32)u7 << 16);
  *(uint4*)(Abf + off) = o;
}

// ---- W (f32) -> bf16, all 3 blocks at once ----
__global__ __launch_bounds__(256) void cvtW_kernel(const float* __restrict__ Wc,
                                                   const float* __restrict__ Wg,
                                                   unsigned short* __restrict__ Wbf) {
  int e = blockIdx.x * 256 + threadIdx.x;  // 0..98303
  if (e < NB * C * C) Wbf[e] = f2bf(Wc[e]);
  else Wbf[e] = f2bf(Wg[e - NB * C * C]);
}

// ---- fused per-block-iter: gather-sum (bf16) + dual MFMA matmul + epilogue
// 256 blocks x 512 threads (8 waves), XCD-pair swizzled. Block = RB=64 rows:
// halves per-iter weight re-read traffic (16MB vs 32MB) and gives each wave
// FOUR independent MFMA row-tile chains (vs 2) for matrix-pipe ILP. Weight
// B-operands prefetched before the gather (r19); LDS-staged coalesced
// epilogue with early Pcur read. LDS 53.4KB -> 2 blocks/CU (16 waves, same
// as r19). Per-element arithmetic and op order identical to r19.
__global__ __launch_bounds__(512) void fused_kernel(
    const float* __restrict__ Pcur, const unsigned short* __restrict__ Abf,
    const int* __restrict__ idx,
    const unsigned short* __restrict__ Wcbf, const unsigned short* __restrict__ Wgbf,
    const float* __restrict__ bc, const float* __restrict__ bg,
    float* __restrict__ Pnxt, unsigned short* __restrict__ AbfN) {
  __shared__ int ji[RB * K];              // 4 KB
  __shared__ unsigned short Sl[RB][136];  // 17.4 KB (+8 pad)
  __shared__ float Pst[RB][128];          // 32 KB epilogue staging
  int bb, rgrp;
  swz_batch(blockIdx.x, &bb, &rgrp);      // 256 blocks: rgrp 0..63
  int row0 = bb * N + rgrp * RB;          // global row
  int tid = threadIdx.x;
  ji[tid] = idx[row0 * K + tid];          // RB*K = 1024 = 2x blockDim
  ji[tid + 512] = idx[row0 * K + tid + 512];
  __syncthreads();

  // batch base for neighbor indices (idx entries are within-batch!)
  const unsigned short* AbfB = Abf + ((size_t)bb << 12) * C;

  // prefetch weight B-operands now: 8 x 16B/lane in flight across the gather
  int lane = tid & 63, wave = tid >> 6;  // 8 waves
  int lrow = lane & 15;
  int kgrp = (lane >> 4) * 8;
  int ct = wave;
  const unsigned short* wcp = Wcbf + (size_t)(ct * 16 + lrow) * C + kgrp;
  const unsigned short* wgp = Wgbf + (size_t)(ct * 16 + lrow) * C + kgrp;
  short8_t bCw[4], bGw[4];
#pragma unroll
  for (int ks = 0; ks < 4; ++ks) {
    bCw[ks] = *(const short8_t*)(wcp + ks * 32);
    bGw[ks] = *(const short8_t*)(wgp + ks * 32);
  }

  // gather: item (r,g) sums 8 cols [g*8, g*8+8) of row r over 16 neighbors;
  // 64 rows x 16 groups = 1024 items, 2 per thread
#pragma unroll
  for (int it = 0; it < 2; ++it) {
    int item = tid + it * 512;
    int r = item >> 4, g = item & 15;  // r 0..63
    float s0 = 0.f, s1 = 0.f, s2 = 0.f, s3 = 0.f, s4 = 0.f, s5 = 0.f, s6 = 0.f, s7 = 0.f;
#pragma unroll
    for (int t = 0; t < K; ++t) {
      int j = ji[(r << 4) + t];
      uint4 v = *(const uint4*)(AbfB + (size_t)j * C + g * 8);
      s0 += bflo(v.x); s1 += bfhi(v.x);
      s2 += bflo(v.y); s3 += bfhi(v.y);
      s4 += bflo(v.z); s5 += bfhi(v.z);
      s6 += bflo(v.w); s7 += bfhi(v.w);
    }
    uint4 o;
    o.x = (u32)f2bf(s0) | ((u32)f2bf(s1) << 16);
    o.y = (u32)f2bf(s2) | ((u32)f2bf(s3) << 16);
    o.z = (u32)f2bf(s4) | ((u32)f2bf(s5) << 16);
    o.w = (u32)f2bf(s6) | ((u32)f2bf(s7) << 16);
    *(uint4*)(&Sl[r][g * 8]) = o;
  }
  __syncthreads();

  // MFMA: wave = col-tile ct (16 cols); 4 row-tiles (rows rt*16..rt*16+15).
  // A row = lane&15, k-chunk = (lane>>4)*8 ; B col = lane&15, same k-chunk.
  f32x4 acc[4];
#pragma unroll
  for (int rt = 0; rt < 4; ++rt) acc[rt] = (f32x4){0.f, 0.f, 0.f, 0.f};
#pragma unroll
  for (int ks = 0; ks < 4; ++ks) {
#pragma unroll
    for (int rt = 0; rt < 4; ++rt) {
      const unsigned short* ap = Abf + (size_t)(row0 + rt * 16 + lrow) * C + kgrp;
      short8_t av = *(const short8_t*)(ap + ks * 32);
      acc[rt] = __builtin_amdgcn_mfma_f32_16x16x32_bf16(av, bCw[ks], acc[rt], 0, 0, 0);
    }
  }
#pragma unroll
  for (int ks = 0; ks < 4; ++ks) {
#pragma unroll
    for (int rt = 0; rt < 4; ++rt) {
      short8_t sv = *(const short8_t*)(&Sl[rt * 16 + lrow][kgrp + ks * 32]);
      acc[rt] = __builtin_amdgcn_mfma_f32_16x16x32_bf16(sv, bGw[ks], acc[rt], 0, 0, 0);
    }
  }

  // issue the epilogue's Pcur reads early (hide L2/L3 latency under barrier)
  float4 pv[4];
  size_t goff[2];
#pragma unroll
  for (int it = 0; it < 2; ++it) {
    int item = tid + it * 512;
    int er = item >> 4;
    int ec8 = (item & 15) * 8;
    goff[it] = (size_t)(row0 + er) * C + ec8;
    pv[it * 2] = *(const float4*)&Pcur[goff[it]];
    pv[it * 2 + 1] = *(const float4*)&Pcur[goff[it] + 4];
  }

  // stage fragments: D row=(lane>>4)*4+q, col=lane&15 (within 16x16 tile)
  {
    int colw = ct * 16 + lrow;
    int rbase = (lane >> 4) * 4;
#pragma unroll
    for (int rt = 0; rt < 4; ++rt) {
#pragma unroll
      for (int q = 0; q < 4; ++q) {
        Pst[rt * 16 + rbase + q][colw] = acc[rt][q];
      }
    }
  }
  __syncthreads();

  // coalesced epilogue: item -> (row, 8 cols); float4/uint4 global I/O
#pragma unroll
  for (int it = 0; it < 2; ++it) {
    int item = tid + it * 512;
    int er = item >> 4;
    int ec8 = (item & 15) * 8;
    float4 av = *(const float4*)&Pst[er][ec8];
    float4 aw = *(const float4*)&Pst[er][ec8 + 4];
    float4 bcv0 = *(const float4*)&bc[ec8];
    float4 bcv1 = *(const float4*)&bc[ec8 + 4];
    float4 bgv0 = *(const float4*)&bg[ec8];
    float4 bgv1 = *(const float4*)&bg[ec8 + 4];
    float4 pv0 = pv[it * 2], pv1 = pv[it * 2 + 1];
    float4 o0, o1;
    o0.x = (av.x + (bcv0.x + 16.0f * bgv0.x)) * (1.0f / 17.0f) + pv0.x;
    o0.y = (av.y + (bcv0.y + 16.0f * bgv0.y)) * (1.0f / 17.0f) + pv0.y;
    o0.z = (av.z + (bcv0.z + 16.0f * bgv0.z)) * (1.0f / 17.0f) + pv0.z;
    o0.w = (av.w + (bcv0.w + 16.0f * bgv0.w)) * (1.0f / 17.0f) + pv0.w;
    o1.x = (aw.x + (bcv1.x + 16.0f * bgv1.x)) * (1.0f / 17.0f) + pv1.x;
    o1.y = (aw.y + (bcv1.y + 16.0f * bgv1.y)) * (1.0f / 17.0f) + pv1.y;
    o1.z = (aw.z + (bcv1.z + 16.0f * bgv1.z)) * (1.0f / 17.0f) + pv1.z;
    o1.w = (aw.w + (bcv1.w + 16.0f * bgv1.w)) * (1.0f / 17.0f) + pv1.w;
    *(float4*)&Pnxt[goff[it]] = o0;
    *(float4*)&Pnxt[goff[it] + 4] = o1;
    if (AbfN) {
      uint4 ob;
      ob.x = (u32)f2bf(leaky(o0.x)) | ((u32)f2bf(leaky(o0.y)) << 16);
      ob.y = (u32)f2bf(leaky(o0.z)) | ((u32)f2bf(leaky(o0.w)) << 16);
      ob.z = (u32)f2bf(leaky(o1.x)) | ((u32)f2bf(leaky(o1.y)) << 16);
      ob.w = (u32)f2bf(leaky(o1.z)) | ((u32)f2bf(leaky(o1.w)) << 16);
      *(uint4*)(AbfN + goff[it]) = ob;
    }
  }
}

extern "C" void kernel_launch(void* const* d_in, const int* in_sizes, int n_in,
                              void* d_out, int out_size, void* d_ws, size_t ws_size,
                              hipStream_t stream) {
  const float* xyz = (const float*)d_in[0];
  const float* pts = (const float*)d_in[1];
  const float* Wc = (const float*)d_in[5];
  const float* bc = (const float*)d_in[6];
  const float* Wg = (const float*)d_in[7];
  const float* bg = (const float*)d_in[8];

  const size_t PE = (size_t)B * N * C;            // 2097152 elements
  const size_t idxB = (size_t)B * N * K * 4;      // 1 MB
  const size_t WbfB = (size_t)2 * NB * C * C * 2; // 192 KB
  char* ws = (char*)d_ws;
  float* Pa            = (float*)ws;                                  // 8 MB
  int* idx             = (int*)(ws + PE * 4);                         // 1 MB
  unsigned short* Abf0 = (unsigned short*)(ws + PE * 4 + idxB);       // 4 MB
  unsigned short* Wbf  = (unsigned short*)(ws + PE * 4 + idxB + PE * 2);
  unsigned short* Abf1 = (unsigned short*)(ws + PE * 4 + idxB + PE * 2 + WbfB);
  unsigned short* Wcbf = Wbf;
  unsigned short* Wgbf = Wbf + (size_t)NB * C * C;
  const size_t need = PE * 4 + idxB + PE * 2 + WbfB + PE * 2;  // 17.2 MB
  const bool fusedAbf = (ws_size >= need);

  hipLaunchKernelGGL(cvtW_kernel, dim3((2 * NB * C * C) / 256), dim3(256), 0, stream,
                     Wc, Wg, Wbf);
  hipLaunchKernelGGL(cvtA_kernel, dim3(1024), dim3(256), 0, stream, pts, Abf0);
  hipLaunchKernelGGL(knn_kernel, dim3(2048), dim3(512), 0, stream, xyz, idx);

  // ping-pong: pts (read-only) -> d_out -> Pa -> d_out
  const float* cur = pts;
  float* nxt = (float*)d_out;
  unsigned short* AbfCur = Abf0;
  unsigned short* AbfNxt = fusedAbf ? Abf1 : Abf0;
  for (int i = 0; i < NB; ++i) {
    if (!fusedAbf && i > 0) {
      hipLaunchKernelGGL(cvtA_kernel, dim3(1024), dim3(256), 0, stream, cur, Abf0);
      AbfCur = Abf0;
    }
    unsigned short* an = (fusedAbf && i < NB - 1) ? AbfNxt : (unsigned short*)nullptr;
    hipLaunchKernelGGL(fused_kernel, dim3((B * N) / RB), dim3(512), 0, stream,
                       cur, AbfCur, idx, Wcbf + (size_t)i * C * C, Wgbf + (size_t)i * C * C,
                       bc + (size_t)i * C, bg + (size_t)i * C, nxt, an);
    cur = nxt;
    nxt = (i == 0) ? Pa : (float*)d_out;
    if (fusedAbf) { unsigned short* ta = AbfCur; AbfCur = AbfNxt; AbfNxt = ta; }
  }
}

// Round 21
// 87.401 us; speedup vs baseline: 1.2720x; 1.0706x over previous
//
#include <hip/hip_runtime.h>
#include <math.h>

#define B  4
#define N  4096
#define C  128
#define K  16
#define NB 3
#define RB 64  // fused: rows per block

typedef unsigned int u32;
typedef unsigned long long u64;
typedef __attribute__((ext_vector_type(8))) short short8_t;
typedef __attribute__((ext_vector_type(4))) float f32x4;

__device__ __forceinline__ float leaky(float x) {
  return x >= 0.f ? x : 0.01f * x;
}
__device__ __forceinline__ unsigned short f2bf(float f) {
  u32 x = __float_as_uint(f);
  return (unsigned short)((x + 0x7FFFu + ((x >> 16) & 1u)) >> 16);  // RNE
}
__device__ __forceinline__ float bflo(u32 u) { return __uint_as_float(u << 16); }
__device__ __forceinline__ float bfhi(u32 u) { return __uint_as_float(u & 0xFFFF0000u); }
__device__ __forceinline__ u32 umaxu(u32 a, u32 b) { return a > b ? a : b; }

// XCD-pair swizzle: bidx=(q*8+x) -> batch b=x>>1, row-group rgrp=2q+(x&1).
__device__ __forceinline__ void swz_batch(int bidx, int* b, int* rgrp) {
  int q = bidx >> 3, x = bidx & 7;
  *b = x >> 1;
  *rgrp = (q << 1) | (x & 1);
}

// 64-lane max reduce, pure VALU via DPP. Result valid in lane 63.
__device__ __forceinline__ u32 dpp_max64(u32 v) {
  v = umaxu(v, (u32)__builtin_amdgcn_update_dpp(0, (int)v, 0x111, 0xf, 0xf, false));
  v = umaxu(v, (u32)__builtin_amdgcn_update_dpp(0, (int)v, 0x112, 0xf, 0xf, false));
  v = umaxu(v, (u32)__builtin_amdgcn_update_dpp(0, (int)v, 0x114, 0xf, 0xf, false));
  v = umaxu(v, (u32)__builtin_amdgcn_update_dpp(0, (int)v, 0x118, 0xf, 0xf, false));
  v = umaxu(v, (u32)__builtin_amdgcn_update_dpp(0, (int)v, 0x142, 0xa, 0xf, false));
  v = umaxu(v, (u32)__builtin_amdgcn_update_dpp(0, (int)v, 0x143, 0xc, 0xf, false));
  return v;
}

// exact monotone-encoded squared distance (reference op order, no contraction)
__device__ __forceinline__ u32 encdist(float xi, float yi, float zi, float sqi,
                                       float4 pj) {
  float dt = __fadd_rn(__fmul_rn(xi, pj.x), __fmul_rn(yi, pj.y));
  dt = __fadd_rn(dt, __fmul_rn(zi, pj.z));
  float dd = __fsub_rn(__fadd_rn(sqi, pj.w), __fmul_rn(2.0f, dt));
  u32 bits = __float_as_uint(dd);
  return bits ^ ((u32)(((int)bits) >> 31) | 0x80000000u);
}

// cheap approximate distance (fma contraction allowed), clamped to >= 0.
// Used ONLY for the tau threshold / survivor predicate (with 1-quantum slack);
// exact encdist is recomputed for all survivors.
__device__ __forceinline__ float apxdist(float xi, float yi, float zi, float sqi,
                                         float4 pj) {
  float dd = (sqi + pj.w) - 2.0f * (xi * pj.x + (yi * pj.y + zi * pj.z));
  return fmaxf(dd, 0.0f);
}

// ---- KNN (faithful: k+1 LARGEST sq-dists, drop first) ----
// Round-16 version verbatim (best measured: 47.7us, VGPR 52; FROZEN — r12/13/
// 14/17 structural variants all regressed). 2048 blocks x 512 threads.
__global__ __launch_bounds__(512) void knn_kernel(const float* __restrict__ xyz,
                                                  int* __restrict__ idxOut) {
  __shared__ float4 p[N];       // 64 KB
  __shared__ u64 surv[8][64];   // 4 KB survivor buffer, per wave
  int bidx = blockIdx.x;
  int b = bidx >> 9;            // 512 blocks per batch
  int row0 = (bidx & 511) << 3; // 8 rows per block
  const float* src = xyz + b * N * 3;
  int tid = threadIdx.x;

  for (int e = tid; e < N; e += 512) {
    float x = src[3 * e], y = src[3 * e + 1], z = src[3 * e + 2];
    // sq = (x*x + y*y) + z*z, exact f32 rounding, no FMA contraction
    float sq = __fadd_rn(__fadd_rn(__fmul_rn(x, x), __fmul_rn(y, y)), __fmul_rn(z, z));
    p[e] = make_float4(x, y, z, sq);
  }
  __syncthreads();

  int lane = tid & 63;
  int wave = tid >> 6;   // 0..7 = local row
  int i = row0 + wave;   // query point within batch

  float4 pi = p[i];
  float xi = pi.x, yi = pi.y, zi = pi.z, sqi = pi.w;

  // Phase A: approx distances; pack hi16; float running max
  u32 denc16[32];
  float fmx = 0.0f;
#pragma unroll
  for (int t2 = 0; t2 < 32; ++t2) {
    int t0 = t2 * 2, t1 = t0 + 1;
    float4 pj0 = p[lane + (t0 << 6)];
    float4 pj1 = p[lane + (t1 << 6)];
    float d0 = apxdist(xi, yi, zi, sqi, pj0);
    float d1 = apxdist(xi, yi, zi, sqi, pj1);
    fmx = fmaxf(fmx, fmaxf(d0, d1));
    denc16[t2] = (__float_as_uint(d0) >> 16) | (__float_as_uint(d1) & 0xFFFF0000u);
  }

  // Phase B: sort the 64 lane-max values (u32 bits, all >= +0) descending
  u32 sv = __float_as_uint(fmx);
#pragma unroll
  for (int k2 = 2; k2 <= 64; k2 <<= 1) {
#pragma unroll
    for (int jj = k2 >> 1; jj > 0; jj >>= 1) {
      u32 ov = (u32)__shfl_xor((int)sv, jj, 64);
      bool keepMax = ((lane & jj) == 0) == ((lane & k2) == 0);
      sv = (keepMax == (ov > sv)) ? ov : sv;
    }
  }
  u32 th = ((u32)__shfl((int)sv, 16, 64)) >> 16;
  u32 tau16 = (th > 0u) ? (th - 1u) : 0u;  // 1-quantum slack (superset)

  // Phase C: ballot-compact candidates with hi16(approx) >= tau16; exact keys
  int total = 0;
#pragma unroll
  for (int t = 0; t < 64; ++t) {
    u32 h = (t & 1) ? (denc16[t >> 1] >> 16) : (denc16[t >> 1] & 0xFFFFu);
    bool pred = (h >= tau16);
    u64 bal = __ballot(pred);
    if (bal != 0ull) {  // wave-uniform skip of empty slots
      int pos = total + (int)__builtin_amdgcn_mbcnt_hi(
                            (u32)(bal >> 32),
                            __builtin_amdgcn_mbcnt_lo((u32)bal, 0u));
      if (pred && pos < 64) {
        u32 enc = encdist(xi, yi, zi, sqi, p[lane + (t << 6)]);  // exact
        surv[wave][pos] = ((u64)enc << 32) | (u32)(4095 - (lane + (t << 6)));
      }
      total += (int)__popcll(bal);
    }
  }

  if (total <= 64) {
    // Phase D: sort survivors descending (zeros pad to the end), emit 1..16.
    u64 sk = (lane < total) ? surv[wave][lane] : 0ull;
#pragma unroll
    for (int k2 = 2; k2 <= 64; k2 <<= 1) {
#pragma unroll
      for (int jj = k2 >> 1; jj > 0; jj >>= 1) {
        u64 ok = __shfl_xor(sk, jj, 64);
        bool keepMax = ((lane & jj) == 0) == ((lane & k2) == 0);
        sk = (keepMax == (ok > sk)) ? ok : sk;
      }
    }
    if (lane >= 1 && lane < 17) {
      idxOut[((long long)(b * N + i)) * K + lane - 1] = 4095 - (int)(u32)sk;
    }
  } else {
    // Fallback (degenerate ties; never on this input): exact iterative
    // extraction; recomputes its own exact argmax first.
    u32 cmax = 0u; u32 ct = 0u;
#pragma unroll
    for (int t = 0; t < 64; ++t) {
      u32 enc = encdist(xi, yi, zi, sqi, p[lane + (t << 6)]);
      if (enc > cmax) { cmax = enc; ct = (u32)t; }
    }
    u64 elim = 0ull;
    for (int r = 0; r < 17; ++r) {
      u32 wmax = dpp_max64(cmax);
      u32 s_wmax = (u32)__builtin_amdgcn_readlane((int)wmax, 63);
      u64 mask = __ballot(cmax == s_wmax);
      int s_wj;
      if (__popcll(mask) == 1) {
        int l = (int)(__ffsll((long long)mask) - 1);
        int myj = lane + ((int)ct << 6);
        s_wj = __builtin_amdgcn_readlane(myj, l);
      } else {
        u32 jv = (cmax == s_wmax) ? (u32)(lane + ((int)ct << 6)) : 0xFFFFFFFFu;
#pragma unroll
        for (int off = 1; off < 64; off <<= 1) {
          u32 oj = (u32)__shfl_xor((int)jv, off, 64);
          jv = oj < jv ? oj : jv;
        }
        s_wj = (int)__builtin_amdgcn_readfirstlane((int)jv);
      }
      if (r > 0 && lane == 0)
        idxOut[((long long)(b * N + i)) * K + (r - 1)] = s_wj;
      if (r == 16) break;
      if (lane == (s_wj & 63)) {
        elim |= 1ull << (s_wj >> 6);
        cmax = 0u; ct = 0u;
        for (int t = 0; t < 64; ++t) {
          if (elim & (1ull << t)) continue;
          u32 enc = encdist(xi, yi, zi, sqi, p[lane + (t << 6)]);
          if (enc > cmax) { cmax = enc; ct = (u32)t; }
        }
      }
    }
  }
}

// ---- Abf = bf16(leaky(P)) : XCD-pair swizzled (1024 blocks x 256) ----
__global__ __launch_bounds__(256) void cvtA_kernel(const float* __restrict__ P,
                                                   unsigned short* __restrict__ Abf) {
  int b, rgrp;
  swz_batch(blockIdx.x, &b, &rgrp);
  int tid = threadIdx.x;
  size_t off = ((size_t)b * N + rgrp * 16 + (tid >> 4)) * C + (tid & 15) * 8;
  const float4* p4 = (const float4*)(P + off);
  float4 a = p4[0], c = p4[1];
  unsigned short u0 = f2bf(leaky(a.x)), u1 = f2bf(leaky(a.y));
  unsigned short u2 = f2bf(leaky(a.z)), u3 = f2bf(leaky(a.w));
  unsigned short u4 = f2bf(leaky(c.x)), u5 = f2bf(leaky(c.y));
  unsigned short u6 = f2bf(leaky(c.z)), u7 = f2bf(leaky(c.w));
  uint4 o;
  o.x = (u32)u0 | ((u32)u1 << 16);
  o.y = (u32)u2 | ((u32)u3 << 16);
  o.z = (u32)u4 | ((u32)u5 << 16);
  o.w = (u32)u6 | ((u32)u7 << 16);
  *(uint4*)(Abf + off) = o;
}

// ---- W (f32) -> bf16, all 3 blocks at once ----
__global__ __launch_bounds__(256) void cvtW_kernel(const float* __restrict__ Wc,
                                                   const float* __restrict__ Wg,
                                                   unsigned short* __restrict__ Wbf) {
  int e = blockIdx.x * 256 + threadIdx.x;  // 0..98303
  if (e < NB * C * C) Wbf[e] = f2bf(Wc[e]);
  else Wbf[e] = f2bf(Wg[e - NB * C * C]);
}

// ---- fused per-block-iter: gather-sum (bf16) + dual MFMA matmul + epilogue
// 256 blocks x 512 threads (8 waves), XCD-pair swizzled. Block = RB=64 rows.
// r21: (a) A-tile staged in LDS once per block -- all 8 waves previously
// re-read the same 64 Abf rows from L2 (8x16KB x 256 blocks = 32MB/iter);
// now one cooperative 16KB copy in the pre-gather region, MFMA A-operands
// come from LDS. (b) Pst padded to [RB][132] (row stride 528B = bank 4 mod
// 32) to break the 4-way bank conflict of the fragment-staging stores
// (512B stride put every row on the same 16 banks). LDS 72.6KB -> still
// 2 blocks/CU. Bit-identical MFMA inputs -> identical output.
__global__ __launch_bounds__(512) void fused_kernel(
    const float* __restrict__ Pcur, const unsigned short* __restrict__ Abf,
    const int* __restrict__ idx,
    const unsigned short* __restrict__ Wcbf, const unsigned short* __restrict__ Wgbf,
    const float* __restrict__ bc, const float* __restrict__ bg,
    float* __restrict__ Pnxt, unsigned short* __restrict__ AbfN) {
  __shared__ int ji[RB * K];                                   // 4 KB
  __shared__ unsigned short Sl[RB][136];                       // 17.4 KB
  __shared__ unsigned short Al[RB][136];                       // 17.4 KB A-tile
  __shared__ __attribute__((aligned(16))) float Pst[RB][132];  // 33.8 KB
  int bb, rgrp;
  swz_batch(blockIdx.x, &bb, &rgrp);      // 256 blocks: rgrp 0..63
  int row0 = bb * N + rgrp * RB;          // global row
  int tid = threadIdx.x;
  ji[tid] = idx[row0 * K + tid];          // RB*K = 1024 = 2x blockDim
  ji[tid + 512] = idx[row0 * K + tid + 512];
  __syncthreads();

  // batch base for neighbor indices (idx entries are within-batch!)
  const unsigned short* AbfB = Abf + ((size_t)bb << 12) * C;

  // prefetch weight B-operands now: 8 x 16B/lane in flight across the gather
  int lane = tid & 63, wave = tid >> 6;  // 8 waves
  int lrow = lane & 15;
  int kgrp = (lane >> 4) * 8;
  int ct = wave;
  const unsigned short* wcp = Wcbf + (size_t)(ct * 16 + lrow) * C + kgrp;
  const unsigned short* wgp = Wgbf + (size_t)(ct * 16 + lrow) * C + kgrp;
  short8_t bCw[4], bGw[4];
#pragma unroll
  for (int ks = 0; ks < 4; ++ks) {
    bCw[ks] = *(const short8_t*)(wcp + ks * 32);
    bGw[ks] = *(const short8_t*)(wgp + ks * 32);
  }

  // stage the block's A-tile (64 rows x 256B = 16KB) into LDS: 2 x 16B/thread
#pragma unroll
  for (int it = 0; it < 2; ++it) {
    int item = tid + it * 512;
    int r = item >> 4, g = item & 15;
    *(uint4*)(&Al[r][g * 8]) =
        *(const uint4*)(Abf + (size_t)(row0 + r) * C + g * 8);
  }

  // gather: item (r,g) sums 8 cols [g*8, g*8+8) of row r over 16 neighbors;
  // 64 rows x 16 groups = 1024 items, 2 per thread
#pragma unroll
  for (int it = 0; it < 2; ++it) {
    int item = tid + it * 512;
    int r = item >> 4, g = item & 15;  // r 0..63
    float s0 = 0.f, s1 = 0.f, s2 = 0.f, s3 = 0.f, s4 = 0.f, s5 = 0.f, s6 = 0.f, s7 = 0.f;
#pragma unroll
    for (int t = 0; t < K; ++t) {
      int j = ji[(r << 4) + t];
      uint4 v = *(const uint4*)(AbfB + (size_t)j * C + g * 8);
      s0 += bflo(v.x); s1 += bfhi(v.x);
      s2 += bflo(v.y); s3 += bfhi(v.y);
      s4 += bflo(v.z); s5 += bfhi(v.z);
      s6 += bflo(v.w); s7 += bfhi(v.w);
    }
    uint4 o;
    o.x = (u32)f2bf(s0) | ((u32)f2bf(s1) << 16);
    o.y = (u32)f2bf(s2) | ((u32)f2bf(s3) << 16);
    o.z = (u32)f2bf(s4) | ((u32)f2bf(s5) << 16);
    o.w = (u32)f2bf(s6) | ((u32)f2bf(s7) << 16);
    *(uint4*)(&Sl[r][g * 8]) = o;
  }
  __syncthreads();

  // MFMA: wave = col-tile ct (16 cols); 4 row-tiles (rows rt*16..rt*16+15).
  // A row = lane&15, k-chunk = (lane>>4)*8 ; B col = lane&15, same k-chunk.
  f32x4 acc[4];
#pragma unroll
  for (int rt = 0; rt < 4; ++rt) acc[rt] = (f32x4){0.f, 0.f, 0.f, 0.f};
#pragma unroll
  for (int ks = 0; ks < 4; ++ks) {
#pragma unroll
    for (int rt = 0; rt < 4; ++rt) {
      short8_t av = *(const short8_t*)(&Al[rt * 16 + lrow][kgrp + ks * 32]);
      acc[rt] = __builtin_amdgcn_mfma_f32_16x16x32_bf16(av, bCw[ks], acc[rt], 0, 0, 0);
    }
  }
#pragma unroll
  for (int ks = 0; ks < 4; ++ks) {
#pragma unroll
    for (int rt = 0; rt < 4; ++rt) {
      short8_t sv = *(const short8_t*)(&Sl[rt * 16 + lrow][kgrp + ks * 32]);
      acc[rt] = __builtin_amdgcn_mfma_f32_16x16x32_bf16(sv, bGw[ks], acc[rt], 0, 0, 0);
    }
  }

  // issue the epilogue's Pcur reads early (hide L2/L3 latency under barrier)
  float4 pv[4];
  size_t goff[2];
#pragma unroll
  for (int it = 0; it < 2; ++it) {
    int item = tid + it * 512;
    int er = item >> 4;
    int ec8 = (item & 15) * 8;
    goff[it] = (size_t)(row0 + er) * C + ec8;
    pv[it * 2] = *(const float4*)&Pcur[goff[it]];
    pv[it * 2 + 1] = *(const float4*)&Pcur[goff[it] + 4];
  }

  // stage fragments: D row=(lane>>4)*4+q, col=lane&15 (within 16x16 tile)
  {
    int colw = ct * 16 + lrow;
    int rbase = (lane >> 4) * 4;
#pragma unroll
    for (int rt = 0; rt < 4; ++rt) {
#pragma unroll
      for (int q = 0; q < 4; ++q) {
        Pst[rt * 16 + rbase + q][colw] = acc[rt][q];
      }
    }
  }
  __syncthreads();

  // coalesced epilogue: item -> (row, 8 cols); float4/uint4 global I/O
#pragma unroll
  for (int it = 0; it < 2; ++it) {
    int item = tid + it * 512;
    int er = item >> 4;
    int ec8 = (item & 15) * 8;
    float4 av = *(const float4*)&Pst[er][ec8];
    float4 aw = *(const float4*)&Pst[er][ec8 + 4];
    float4 bcv0 = *(const float4*)&bc[ec8];
    float4 bcv1 = *(const float4*)&bc[ec8 + 4];
    float4 bgv0 = *(const float4*)&bg[ec8];
    float4 bgv1 = *(const float4*)&bg[ec8 + 4];
    float4 pv0 = pv[it * 2], pv1 = pv[it * 2 + 1];
    float4 o0, o1;
    o0.x = (av.x + (bcv0.x + 16.0f * bgv0.x)) * (1.0f / 17.0f) + pv0.x;
    o0.y = (av.y + (bcv0.y + 16.0f * bgv0.y)) * (1.0f / 17.0f) + pv0.y;
    o0.z = (av.z + (bcv0.z + 16.0f * bgv0.z)) * (1.0f / 17.0f) + pv0.z;
    o0.w = (av.w + (bcv0.w + 16.0f * bgv0.w)) * (1.0f / 17.0f) + pv0.w;
    o1.x = (aw.x + (bcv1.x + 16.0f * bgv1.x)) * (1.0f / 17.0f) + pv1.x;
    o1.y = (aw.y + (bcv1.y + 16.0f * bgv1.y)) * (1.0f / 17.0f) + pv1.y;
    o1.z = (aw.z + (bcv1.z + 16.0f * bgv1.z)) * (1.0f / 17.0f) + pv1.z;
    o1.w = (aw.w + (bcv1.w + 16.0f * bgv1.w)) * (1.0f / 17.0f) + pv1.w;
    *(float4*)&Pnxt[goff[it]] = o0;
    *(float4*)&Pnxt[goff[it] + 4] = o1;
    if (AbfN) {
      uint4 ob;
      ob.x = (u32)f2bf(leaky(o0.x)) | ((u32)f2bf(leaky(o0.y)) << 16);
      ob.y = (u32)f2bf(leaky(o0.z)) | ((u32)f2bf(leaky(o0.w)) << 16);
      ob.z = (u32)f2bf(leaky(o1.x)) | ((u32)f2bf(leaky(o1.y)) << 16);
      ob.w = (u32)f2bf(leaky(o1.z)) | ((u32)f2bf(leaky(o1.w)) << 16);
      *(uint4*)(AbfN + goff[it]) = ob;
    }
  }
}

extern "C" void kernel_launch(void* const* d_in, const int* in_sizes, int n_in,
                              void* d_out, int out_size, void* d_ws, size_t ws_size,
                              hipStream_t stream) {
  const float* xyz = (const float*)d_in[0];
  const float* pts = (const float*)d_in[1];
  const float* Wc = (const float*)d_in[5];
  const float* bc = (const float*)d_in[6];
  const float* Wg = (const float*)d_in[7];
  const float* bg = (const float*)d_in[8];

  const size_t PE = (size_t)B * N * C;            // 2097152 elements
  const size_t idxB = (size_t)B * N * K * 4;      // 1 MB
  const size_t WbfB = (size_t)2 * NB * C * C * 2; // 192 KB
  char* ws = (char*)d_ws;
  float* Pa            = (float*)ws;                                  // 8 MB
  int* idx             = (int*)(ws + PE * 4);                         // 1 MB
  unsigned short* Abf0 = (unsigned short*)(ws + PE * 4 + idxB);       // 4 MB
  unsigned short* Wbf  = (unsigned short*)(ws + PE * 4 + idxB + PE * 2);
  unsigned short* Abf1 = (unsigned short*)(ws + PE * 4 + idxB + PE * 2 + WbfB);
  unsigned short* Wcbf = Wbf;
  unsigned short* Wgbf = Wbf + (size_t)NB * C * C;
  const size_t need = PE * 4 + idxB + PE * 2 + WbfB + PE * 2;  // 17.2 MB
  const bool fusedAbf = (ws_size >= need);

  hipLaunchKernelGGL(cvtW_kernel, dim3((2 * NB * C * C) / 256), dim3(256), 0, stream,
                     Wc, Wg, Wbf);
  hipLaunchKernelGGL(cvtA_kernel, dim3(1024), dim3(256), 0, stream, pts, Abf0);
  hipLaunchKernelGGL(knn_kernel, dim3(2048), dim3(512), 0, stream, xyz, idx);

  // ping-pong: pts (read-only) -> d_out -> Pa -> d_out
  const float* cur = pts;
  float* nxt = (float*)d_out;
  unsigned short* AbfCur = Abf0;
  unsigned short* AbfNxt = fusedAbf ? Abf1 : Abf0;
  for (int i = 0; i < NB; ++i) {
    if (!fusedAbf && i > 0) {
      hipLaunchKernelGGL(cvtA_kernel, dim3(1024), dim3(256), 0, stream, cur, Abf0);
      AbfCur = Abf0;
    }
    unsigned short* an = (fusedAbf && i < NB - 1) ? AbfNxt : (unsigned short*)nullptr;
    hipLaunchKernelGGL(fused_kernel, dim3((B * N) / RB), dim3(512), 0, stream,
                       cur, AbfCur, idx, Wcbf + (size_t)i * C * C, Wgbf + (size_t)i * C * C,
                       bc + (size_t)i * C, bg + (size_t)i * C, nxt, an);
    cur = nxt;
    nxt = (i == 0) ? Pa : (float*)d_out;
    if (fusedAbf) { unsigned short* ta = AbfCur; AbfCur = AbfNxt; AbfNxt = ta; }
  }
}

// Round 22
// 85.623 us; speedup vs baseline: 1.2985x; 1.0208x over previous
//
#include <hip/hip_runtime.h>
#include <math.h>

#define B  4
#define N  4096
#define C  128
#define K  16
#define NB 3
#define RB 64  // fused: rows per block

typedef unsigned int u32;
typedef unsigned long long u64;
typedef __attribute__((ext_vector_type(8))) short short8_t;
typedef __attribute__((ext_vector_type(4))) float f32x4;

__device__ __forceinline__ float leaky(float x) {
  return x >= 0.f ? x : 0.01f * x;
}
__device__ __forceinline__ unsigned short f2bf(float f) {
  u32 x = __float_as_uint(f);
  return (unsigned short)((x + 0x7FFFu + ((x >> 16) & 1u)) >> 16);  // RNE
}
__device__ __forceinline__ float bflo(u32 u) { return __uint_as_float(u << 16); }
__device__ __forceinline__ float bfhi(u32 u) { return __uint_as_float(u & 0xFFFF0000u); }
__device__ __forceinline__ u32 umaxu(u32 a, u32 b) { return a > b ? a : b; }

// XCD-pair swizzle: bidx=(q*8+x) -> batch b=x>>1, row-group rgrp=2q+(x&1).
__device__ __forceinline__ void swz_batch(int bidx, int* b, int* rgrp) {
  int q = bidx >> 3, x = bidx & 7;
  *b = x >> 1;
  *rgrp = (q << 1) | (x & 1);
}

// 64-lane max reduce, pure VALU via DPP. Result valid in lane 63.
__device__ __forceinline__ u32 dpp_max64(u32 v) {
  v = umaxu(v, (u32)__builtin_amdgcn_update_dpp(0, (int)v, 0x111, 0xf, 0xf, false));
  v = umaxu(v, (u32)__builtin_amdgcn_update_dpp(0, (int)v, 0x112, 0xf, 0xf, false));
  v = umaxu(v, (u32)__builtin_amdgcn_update_dpp(0, (int)v, 0x114, 0xf, 0xf, false));
  v = umaxu(v, (u32)__builtin_amdgcn_update_dpp(0, (int)v, 0x118, 0xf, 0xf, false));
  v = umaxu(v, (u32)__builtin_amdgcn_update_dpp(0, (int)v, 0x142, 0xa, 0xf, false));
  v = umaxu(v, (u32)__builtin_amdgcn_update_dpp(0, (int)v, 0x143, 0xc, 0xf, false));
  return v;
}

// exact monotone-encoded squared distance (reference op order, no contraction)
__device__ __forceinline__ u32 encdist(float xi, float yi, float zi, float sqi,
                                       float4 pj) {
  float dt = __fadd_rn(__fmul_rn(xi, pj.x), __fmul_rn(yi, pj.y));
  dt = __fadd_rn(dt, __fmul_rn(zi, pj.z));
  float dd = __fsub_rn(__fadd_rn(sqi, pj.w), __fmul_rn(2.0f, dt));
  u32 bits = __float_as_uint(dd);
  return bits ^ ((u32)(((int)bits) >> 31) | 0x80000000u);
}

// cheap approximate distance (fma contraction allowed), clamped to >= 0.
__device__ __forceinline__ float apxdist(float xi, float yi, float zi, float sqi,
                                         float4 pj) {
  float dd = (sqi + pj.w) - 2.0f * (xi * pj.x + (yi * pj.y + zi * pj.z));
  return fmaxf(dd, 0.0f);
}

// ---- KNN (faithful: k+1 LARGEST sq-dists, drop first) ----
// Round-16 version verbatim (best measured: 47.7us, VGPR 52; FROZEN).
__global__ __launch_bounds__(512) void knn_kernel(const float* __restrict__ xyz,
                                                  int* __restrict__ idxOut) {
  __shared__ float4 p[N];       // 64 KB
  __shared__ u64 surv[8][64];   // 4 KB survivor buffer, per wave
  int bidx = blockIdx.x;
  int b = bidx >> 9;            // 512 blocks per batch
  int row0 = (bidx & 511) << 3; // 8 rows per block
  const float* src = xyz + b * N * 3;
  int tid = threadIdx.x;

  for (int e = tid; e < N; e += 512) {
    float x = src[3 * e], y = src[3 * e + 1], z = src[3 * e + 2];
    // sq = (x*x + y*y) + z*z, exact f32 rounding, no FMA contraction
    float sq = __fadd_rn(__fadd_rn(__fmul_rn(x, x), __fmul_rn(y, y)), __fmul_rn(z, z));
    p[e] = make_float4(x, y, z, sq);
  }
  __syncthreads();

  int lane = tid & 63;
  int wave = tid >> 6;   // 0..7 = local row
  int i = row0 + wave;   // query point within batch

  float4 pi = p[i];
  float xi = pi.x, yi = pi.y, zi = pi.z, sqi = pi.w;

  // Phase A: approx distances; pack hi16; float running max
  u32 denc16[32];
  float fmx = 0.0f;
#pragma unroll
  for (int t2 = 0; t2 < 32; ++t2) {
    int t0 = t2 * 2, t1 = t0 + 1;
    float4 pj0 = p[lane + (t0 << 6)];
    float4 pj1 = p[lane + (t1 << 6)];
    float d0 = apxdist(xi, yi, zi, sqi, pj0);
    float d1 = apxdist(xi, yi, zi, sqi, pj1);
    fmx = fmaxf(fmx, fmaxf(d0, d1));
    denc16[t2] = (__float_as_uint(d0) >> 16) | (__float_as_uint(d1) & 0xFFFF0000u);
  }

  // Phase B: sort the 64 lane-max values (u32 bits, all >= +0) descending
  u32 sv = __float_as_uint(fmx);
#pragma unroll
  for (int k2 = 2; k2 <= 64; k2 <<= 1) {
#pragma unroll
    for (int jj = k2 >> 1; jj > 0; jj >>= 1) {
      u32 ov = (u32)__shfl_xor((int)sv, jj, 64);
      bool keepMax = ((lane & jj) == 0) == ((lane & k2) == 0);
      sv = (keepMax == (ov > sv)) ? ov : sv;
    }
  }
  u32 th = ((u32)__shfl((int)sv, 16, 64)) >> 16;
  u32 tau16 = (th > 0u) ? (th - 1u) : 0u;  // 1-quantum slack (superset)

  // Phase C: ballot-compact candidates with hi16(approx) >= tau16; exact keys
  int total = 0;
#pragma unroll
  for (int t = 0; t < 64; ++t) {
    u32 h = (t & 1) ? (denc16[t >> 1] >> 16) : (denc16[t >> 1] & 0xFFFFu);
    bool pred = (h >= tau16);
    u64 bal = __ballot(pred);
    if (bal != 0ull) {  // wave-uniform skip of empty slots
      int pos = total + (int)__builtin_amdgcn_mbcnt_hi(
                            (u32)(bal >> 32),
                            __builtin_amdgcn_mbcnt_lo((u32)bal, 0u));
      if (pred && pos < 64) {
        u32 enc = encdist(xi, yi, zi, sqi, p[lane + (t << 6)]);  // exact
        surv[wave][pos] = ((u64)enc << 32) | (u32)(4095 - (lane + (t << 6)));
      }
      total += (int)__popcll(bal);
    }
  }

  if (total <= 64) {
    // Phase D: sort survivors descending (zeros pad to the end), emit 1..16.
    u64 sk = (lane < total) ? surv[wave][lane] : 0ull;
#pragma unroll
    for (int k2 = 2; k2 <= 64; k2 <<= 1) {
#pragma unroll
      for (int jj = k2 >> 1; jj > 0; jj >>= 1) {
        u64 ok = __shfl_xor(sk, jj, 64);
        bool keepMax = ((lane & jj) == 0) == ((lane & k2) == 0);
        sk = (keepMax == (ok > sk)) ? ok : sk;
      }
    }
    if (lane >= 1 && lane < 17) {
      idxOut[((long long)(b * N + i)) * K + lane - 1] = 4095 - (int)(u32)sk;
    }
  } else {
    // Fallback (degenerate ties; never on this input): exact iterative
    // extraction; recomputes its own exact argmax first.
    u32 cmax = 0u; u32 ct = 0u;
#pragma unroll
    for (int t = 0; t < 64; ++t) {
      u32 enc = encdist(xi, yi, zi, sqi, p[lane + (t << 6)]);
      if (enc > cmax) { cmax = enc; ct = (u32)t; }
    }
    u64 elim = 0ull;
    for (int r = 0; r < 17; ++r) {
      u32 wmax = dpp_max64(cmax);
      u32 s_wmax = (u32)__builtin_amdgcn_readlane((int)wmax, 63);
      u64 mask = __ballot(cmax == s_wmax);
      int s_wj;
      if (__popcll(mask) == 1) {
        int l = (int)(__ffsll((long long)mask) - 1);
        int myj = lane + ((int)ct << 6);
        s_wj = __builtin_amdgcn_readlane(myj, l);
      } else {
        u32 jv = (cmax == s_wmax) ? (u32)(lane + ((int)ct << 6)) : 0xFFFFFFFFu;
#pragma unroll
        for (int off = 1; off < 64; off <<= 1) {
          u32 oj = (u32)__shfl_xor((int)jv, off, 64);
          jv = oj < jv ? oj : jv;
        }
        s_wj = (int)__builtin_amdgcn_readfirstlane((int)jv);
      }
      if (r > 0 && lane == 0)
        idxOut[((long long)(b * N + i)) * K + (r - 1)] = s_wj;
      if (r == 16) break;
      if (lane == (s_wj & 63)) {
        elim |= 1ull << (s_wj >> 6);
        cmax = 0u; ct = 0u;
        for (int t = 0; t < 64; ++t) {
          if (elim & (1ull << t)) continue;
          u32 enc = encdist(xi, yi, zi, sqi, p[lane + (t << 6)]);
          if (enc > cmax) { cmax = enc; ct = (u32)t; }
        }
      }
    }
  }
}

// ---- Abf = bf16(leaky(P)) : XCD-pair swizzled (1024 blocks x 256) ----
__global__ __launch_bounds__(256) void cvtA_kernel(const float* __restrict__ P,
                                                   unsigned short* __restrict__ Abf) {
  int b, rgrp;
  swz_batch(blockIdx.x, &b, &rgrp);
  int tid = threadIdx.x;
  size_t off = ((size_t)b * N + rgrp * 16 + (tid >> 4)) * C + (tid & 15) * 8;
  const float4* p4 = (const float4*)(P + off);
  float4 a = p4[0], c = p4[1];
  unsigned short u0 = f2bf(leaky(a.x)), u1 = f2bf(leaky(a.y));
  unsigned short u2 = f2bf(leaky(a.z)), u3 = f2bf(leaky(a.w));
  unsigned short u4 = f2bf(leaky(c.x)), u5 = f2bf(leaky(c.y));
  unsigned short u6 = f2bf(leaky(c.z)), u7 = f2bf(leaky(c.w));
  uint4 o;
  o.x = (u32)u0 | ((u32)u1 << 16);
  o.y = (u32)u2 | ((u32)u3 << 16);
  o.z = (u32)u4 | ((u32)u5 << 16);
  o.w = (u32)u6 | ((u32)u7 << 16);
  *(uint4*)(Abf + off) = o;
}

// ---- W (f32) -> bf16, all 3 blocks at once ----
__global__ __launch_bounds__(256) void cvtW_kernel(const float* __restrict__ Wc,
                                                   const float* __restrict__ Wg,
                                                   unsigned short* __restrict__ Wbf) {
  int e = blockIdx.x * 256 + threadIdx.x;  // 0..98303
  if (e < NB * C * C) Wbf[e] = f2bf(Wc[e]);
  else Wbf[e] = f2bf(Wg[e - NB * C * C]);
}

// ---- fused per-block-iter: gather-sum (bf16) + dual MFMA matmul + epilogue
// 256 blocks x 512 threads (8 waves), XCD-pair swizzled. Block = RB=64 rows.
// r22: Pst ALIASES the Al+Sl region (both dead after the MFMA loops) via a
// union -- LDS 72.6 -> 38.9 KB. If the allocator lands <=64 VGPR this gives
// 4 blocks/CU = 32 waves/CU (vs 16). To help it: the early-Pcur read (20
// live regs across staging) is dropped; epilogue reads Pcur directly. One
// extra barrier added between MFMA reads and Pst writes (aliasing hazard).
__global__ __launch_bounds__(512) void fused_kernel(
    const float* __restrict__ Pcur, const unsigned short* __restrict__ Abf,
    const int* __restrict__ idx,
    const unsigned short* __restrict__ Wcbf, const unsigned short* __restrict__ Wgbf,
    const float* __restrict__ bc, const float* __restrict__ bg,
    float* __restrict__ Pnxt, unsigned short* __restrict__ AbfN) {
  union SmemU {
    struct { unsigned short Al[RB][136]; unsigned short Sl[RB][136]; } ab;  // 34.8 KB
    __attribute__((aligned(16))) float Pst[RB][132];                        // 33.8 KB
  };
  __shared__ SmemU su;       // 34.8 KB (union)
  __shared__ int ji[RB * K]; // 4 KB
  int bb, rgrp;
  swz_batch(blockIdx.x, &bb, &rgrp);      // 256 blocks: rgrp 0..63
  int row0 = bb * N + rgrp * RB;          // global row
  int tid = threadIdx.x;
  ji[tid] = idx[row0 * K + tid];          // RB*K = 1024 = 2x blockDim
  ji[tid + 512] = idx[row0 * K + tid + 512];
  __syncthreads();

  // batch base for neighbor indices (idx entries are within-batch!)
  const unsigned short* AbfB = Abf + ((size_t)bb << 12) * C;

  // prefetch weight B-operands now: 8 x 16B/lane in flight across the gather
  int lane = tid & 63, wave = tid >> 6;  // 8 waves
  int lrow = lane & 15;
  int kgrp = (lane >> 4) * 8;
  int ct = wave;
  const unsigned short* wcp = Wcbf + (size_t)(ct * 16 + lrow) * C + kgrp;
  const unsigned short* wgp = Wgbf + (size_t)(ct * 16 + lrow) * C + kgrp;
  short8_t bCw[4], bGw[4];
#pragma unroll
  for (int ks = 0; ks < 4; ++ks) {
    bCw[ks] = *(const short8_t*)(wcp + ks * 32);
    bGw[ks] = *(const short8_t*)(wgp + ks * 32);
  }

  // stage the block's A-tile (64 rows x 256B = 16KB) into LDS: 2 x 16B/thread
#pragma unroll
  for (int it = 0; it < 2; ++it) {
    int item = tid + it * 512;
    int r = item >> 4, g = item & 15;
    *(uint4*)(&su.ab.Al[r][g * 8]) =
        *(const uint4*)(Abf + (size_t)(row0 + r) * C + g * 8);
  }

  // gather: item (r,g) sums 8 cols [g*8, g*8+8) of row r over 16 neighbors;
  // 64 rows x 16 groups = 1024 items, 2 per thread
#pragma unroll
  for (int it = 0; it < 2; ++it) {
    int item = tid + it * 512;
    int r = item >> 4, g = item & 15;  // r 0..63
    float s0 = 0.f, s1 = 0.f, s2 = 0.f, s3 = 0.f, s4 = 0.f, s5 = 0.f, s6 = 0.f, s7 = 0.f;
#pragma unroll
    for (int t = 0; t < K; ++t) {
      int j = ji[(r << 4) + t];
      uint4 v = *(const uint4*)(AbfB + (size_t)j * C + g * 8);
      s0 += bflo(v.x); s1 += bfhi(v.x);
      s2 += bflo(v.y); s3 += bfhi(v.y);
      s4 += bflo(v.z); s5 += bfhi(v.z);
      s6 += bflo(v.w); s7 += bfhi(v.w);
    }
    uint4 o;
    o.x = (u32)f2bf(s0) | ((u32)f2bf(s1) << 16);
    o.y = (u32)f2bf(s2) | ((u32)f2bf(s3) << 16);
    o.z = (u32)f2bf(s4) | ((u32)f2bf(s5) << 16);
    o.w = (u32)f2bf(s6) | ((u32)f2bf(s7) << 16);
    *(uint4*)(&su.ab.Sl[r][g * 8]) = o;
  }
  __syncthreads();

  // MFMA: wave = col-tile ct (16 cols); 4 row-tiles (rows rt*16..rt*16+15).
  // A row = lane&15, k-chunk = (lane>>4)*8 ; B col = lane&15, same k-chunk.
  f32x4 acc[4];
#pragma unroll
  for (int rt = 0; rt < 4; ++rt) acc[rt] = (f32x4){0.f, 0.f, 0.f, 0.f};
#pragma unroll
  for (int ks = 0; ks < 4; ++ks) {
#pragma unroll
    for (int rt = 0; rt < 4; ++rt) {
      short8_t av = *(const short8_t*)(&su.ab.Al[rt * 16 + lrow][kgrp + ks * 32]);
      acc[rt] = __builtin_amdgcn_mfma_f32_16x16x32_bf16(av, bCw[ks], acc[rt], 0, 0, 0);
    }
  }
#pragma unroll
  for (int ks = 0; ks < 4; ++ks) {
#pragma unroll
    for (int rt = 0; rt < 4; ++rt) {
      short8_t sv = *(const short8_t*)(&su.ab.Sl[rt * 16 + lrow][kgrp + ks * 32]);
      acc[rt] = __builtin_amdgcn_mfma_f32_16x16x32_bf16(sv, bGw[ks], acc[rt], 0, 0, 0);
    }
  }
  __syncthreads();  // all waves done reading Al/Sl before Pst overwrites them

  // stage fragments: D row=(lane>>4)*4+q, col=lane&15 (within 16x16 tile)
  {
    int colw = ct * 16 + lrow;
    int rbase = (lane >> 4) * 4;
#pragma unroll
    for (int rt = 0; rt < 4; ++rt) {
#pragma unroll
      for (int q = 0; q < 4; ++q) {
        su.Pst[rt * 16 + rbase + q][colw] = acc[rt][q];
      }
    }
  }
  __syncthreads();

  // coalesced epilogue: item -> (row, 8 cols); float4/uint4 global I/O
#pragma unroll
  for (int it = 0; it < 2; ++it) {
    int item = tid + it * 512;
    int er = item >> 4;
    int ec8 = (item & 15) * 8;
    size_t goff = (size_t)(row0 + er) * C + ec8;
    float4 pv0 = *(const float4*)&Pcur[goff];
    float4 pv1 = *(const float4*)&Pcur[goff + 4];
    float4 av = *(const float4*)&su.Pst[er][ec8];
    float4 aw = *(const float4*)&su.Pst[er][ec8 + 4];
    float4 bcv0 = *(const float4*)&bc[ec8];
    float4 bcv1 = *(const float4*)&bc[ec8 + 4];
    float4 bgv0 = *(const float4*)&bg[ec8];
    float4 bgv1 = *(const float4*)&bg[ec8 + 4];
    float4 o0, o1;
    o0.x = (av.x + (bcv0.x + 16.0f * bgv0.x)) * (1.0f / 17.0f) + pv0.x;
    o0.y = (av.y + (bcv0.y + 16.0f * bgv0.y)) * (1.0f / 17.0f) + pv0.y;
    o0.z = (av.z + (bcv0.z + 16.0f * bgv0.z)) * (1.0f / 17.0f) + pv0.z;
    o0.w = (av.w + (bcv0.w + 16.0f * bgv0.w)) * (1.0f / 17.0f) + pv0.w;
    o1.x = (aw.x + (bcv1.x + 16.0f * bgv1.x)) * (1.0f / 17.0f) + pv1.x;
    o1.y = (aw.y + (bcv1.y + 16.0f * bgv1.y)) * (1.0f / 17.0f) + pv1.y;
    o1.z = (aw.z + (bcv1.z + 16.0f * bgv1.z)) * (1.0f / 17.0f) + pv1.z;
    o1.w = (aw.w + (bcv1.w + 16.0f * bgv1.w)) * (1.0f / 17.0f) + pv1.w;
    *(float4*)&Pnxt[goff] = o0;
    *(float4*)&Pnxt[goff + 4] = o1;
    if (AbfN) {
      uint4 ob;
      ob.x = (u32)f2bf(leaky(o0.x)) | ((u32)f2bf(leaky(o0.y)) << 16);
      ob.y = (u32)f2bf(leaky(o0.z)) | ((u32)f2bf(leaky(o0.w)) << 16);
      ob.z = (u32)f2bf(leaky(o1.x)) | ((u32)f2bf(leaky(o1.y)) << 16);
      ob.w = (u32)f2bf(leaky(o1.z)) | ((u32)f2bf(leaky(o1.w)) << 16);
      *(uint4*)(AbfN + goff) = ob;
    }
  }
}

extern "C" void kernel_launch(void* const* d_in, const int* in_sizes, int n_in,
                              void* d_out, int out_size, void* d_ws, size_t ws_size,
                              hipStream_t stream) {
  const float* xyz = (const float*)d_in[0];
  const float* pts = (const float*)d_in[1];
  const float* Wc = (const float*)d_in[5];
  const float* bc = (const float*)d_in[6];
  const float* Wg = (const float*)d_in[7];
  const float* bg = (const float*)d_in[8];

  const size_t PE = (size_t)B * N * C;            // 2097152 elements
  const size_t idxB = (size_t)B * N * K * 4;      // 1 MB
  const size_t WbfB = (size_t)2 * NB * C * C * 2; // 192 KB
  char* ws = (char*)d_ws;
  float* Pa            = (float*)ws;                                  // 8 MB
  int* idx             = (int*)(ws + PE * 4);                         // 1 MB
  unsigned short* Abf0 = (unsigned short*)(ws + PE * 4 + idxB);       // 4 MB
  unsigned short* Wbf  = (unsigned short*)(ws + PE * 4 + idxB + PE * 2);
  unsigned short* Abf1 = (unsigned short*)(ws + PE * 4 + idxB + PE * 2 + WbfB);
  unsigned short* Wcbf = Wbf;
  unsigned short* Wgbf = Wbf + (size_t)NB * C * C;
  const size_t need = PE * 4 + idxB + PE * 2 + WbfB + PE * 2;  // 17.2 MB
  const bool fusedAbf = (ws_size >= need);

  hipLaunchKernelGGL(cvtW_kernel, dim3((2 * NB * C * C) / 256), dim3(256), 0, stream,
                     Wc, Wg, Wbf);
  hipLaunchKernelGGL(cvtA_kernel, dim3(1024), dim3(256), 0, stream, pts, Abf0);
  hipLaunchKernelGGL(knn_kernel, dim3(2048), dim3(512), 0, stream, xyz, idx);

  // ping-pong: pts (read-only) -> d_out -> Pa -> d_out
  const float* cur = pts;
  float* nxt = (float*)d_out;
  unsigned short* AbfCur = Abf0;
  unsigned short* AbfNxt = fusedAbf ? Abf1 : Abf0;
  for (int i = 0; i < NB; ++i) {
    if (!fusedAbf && i > 0) {
      hipLaunchKernelGGL(cvtA_kernel, dim3(1024), dim3(256), 0, stream, cur, Abf0);
      AbfCur = Abf0;
    }
    unsigned short* an = (fusedAbf && i < NB - 1) ? AbfNxt : (unsigned short*)nullptr;
    hipLaunchKernelGGL(fused_kernel, dim3((B * N) / RB), dim3(512), 0, stream,
                       cur, AbfCur, idx, Wcbf + (size_t)i * C * C, Wgbf + (size_t)i * C * C,
                       bc + (size_t)i * C, bg + (size_t)i * C, nxt, an);
    cur = nxt;
    nxt = (i == 0) ? Pa : (float*)d_out;
    if (fusedAbf) { unsigned short* ta = AbfCur; AbfCur = AbfNxt; AbfNxt = ta; }
  }
}

// Round 23
// 85.510 us; speedup vs baseline: 1.3002x; 1.0013x over previous
//
#include <hip/hip_runtime.h>
#include <math.h>

#define B  4
#define N  4096
#define C  128
#define K  16
#define NB 3
#define RB 64  // fused: rows per block

typedef unsigned int u32;
typedef unsigned long long u64;
typedef __attribute__((ext_vector_type(8))) short short8_t;
typedef __attribute__((ext_vector_type(4))) float f32x4;

__device__ __forceinline__ float leaky(float x) {
  return x >= 0.f ? x : 0.01f * x;
}
__device__ __forceinline__ unsigned short f2bf(float f) {
  u32 x = __float_as_uint(f);
  return (unsigned short)((x + 0x7FFFu + ((x >> 16) & 1u)) >> 16);  // RNE
}
__device__ __forceinline__ float bflo(u32 u) { return __uint_as_float(u << 16); }
__device__ __forceinline__ float bfhi(u32 u) { return __uint_as_float(u & 0xFFFF0000u); }
__device__ __forceinline__ u32 umaxu(u32 a, u32 b) { return a > b ? a : b; }

// XCD-pair swizzle: bidx=(q*8+x) -> batch b=x>>1, row-group rgrp=2q+(x&1).
__device__ __forceinline__ void swz_batch(int bidx, int* b, int* rgrp) {
  int q = bidx >> 3, x = bidx & 7;
  *b = x >> 1;
  *rgrp = (q << 1) | (x & 1);
}

// 64-lane max reduce, pure VALU via DPP. Result valid in lane 63.
__device__ __forceinline__ u32 dpp_max64(u32 v) {
  v = umaxu(v, (u32)__builtin_amdgcn_update_dpp(0, (int)v, 0x111, 0xf, 0xf, false));
  v = umaxu(v, (u32)__builtin_amdgcn_update_dpp(0, (int)v, 0x112, 0xf, 0xf, false));
  v = umaxu(v, (u32)__builtin_amdgcn_update_dpp(0, (int)v, 0x114, 0xf, 0xf, false));
  v = umaxu(v, (u32)__builtin_amdgcn_update_dpp(0, (int)v, 0x118, 0xf, 0xf, false));
  v = umaxu(v, (u32)__builtin_amdgcn_update_dpp(0, (int)v, 0x142, 0xa, 0xf, false));
  v = umaxu(v, (u32)__builtin_amdgcn_update_dpp(0, (int)v, 0x143, 0xc, 0xf, false));
  return v;
}

// exact monotone-encoded squared distance (reference op order, no contraction)
__device__ __forceinline__ u32 encdist(float xi, float yi, float zi, float sqi,
                                       float4 pj) {
  float dt = __fadd_rn(__fmul_rn(xi, pj.x), __fmul_rn(yi, pj.y));
  dt = __fadd_rn(dt, __fmul_rn(zi, pj.z));
  float dd = __fsub_rn(__fadd_rn(sqi, pj.w), __fmul_rn(2.0f, dt));
  u32 bits = __float_as_uint(dd);
  return bits ^ ((u32)(((int)bits) >> 31) | 0x80000000u);
}

// cheap approximate distance (fma contraction allowed), clamped to >= 0.
__device__ __forceinline__ float apxdist(float xi, float yi, float zi, float sqi,
                                         float4 pj) {
  float dd = (sqi + pj.w) - 2.0f * (xi * pj.x + (yi * pj.y + zi * pj.z));
  return fmaxf(dd, 0.0f);
}

// ---- KNN (faithful: k+1 LARGEST sq-dists, drop first) ----
// Round-16 version verbatim (best measured: 47.7us, VGPR 52; FROZEN).
__global__ __launch_bounds__(512) void knn_kernel(const float* __restrict__ xyz,
                                                  int* __restrict__ idxOut) {
  __shared__ float4 p[N];       // 64 KB
  __shared__ u64 surv[8][64];   // 4 KB survivor buffer, per wave
  int bidx = blockIdx.x;
  int b = bidx >> 9;            // 512 blocks per batch
  int row0 = (bidx & 511) << 3; // 8 rows per block
  const float* src = xyz + b * N * 3;
  int tid = threadIdx.x;

  for (int e = tid; e < N; e += 512) {
    float x = src[3 * e], y = src[3 * e + 1], z = src[3 * e + 2];
    // sq = (x*x + y*y) + z*z, exact f32 rounding, no FMA contraction
    float sq = __fadd_rn(__fadd_rn(__fmul_rn(x, x), __fmul_rn(y, y)), __fmul_rn(z, z));
    p[e] = make_float4(x, y, z, sq);
  }
  __syncthreads();

  int lane = tid & 63;
  int wave = tid >> 6;   // 0..7 = local row
  int i = row0 + wave;   // query point within batch

  float4 pi = p[i];
  float xi = pi.x, yi = pi.y, zi = pi.z, sqi = pi.w;

  // Phase A: approx distances; pack hi16; float running max
  u32 denc16[32];
  float fmx = 0.0f;
#pragma unroll
  for (int t2 = 0; t2 < 32; ++t2) {
    int t0 = t2 * 2, t1 = t0 + 1;
    float4 pj0 = p[lane + (t0 << 6)];
    float4 pj1 = p[lane + (t1 << 6)];
    float d0 = apxdist(xi, yi, zi, sqi, pj0);
    float d1 = apxdist(xi, yi, zi, sqi, pj1);
    fmx = fmaxf(fmx, fmaxf(d0, d1));
    denc16[t2] = (__float_as_uint(d0) >> 16) | (__float_as_uint(d1) & 0xFFFF0000u);
  }

  // Phase B: sort the 64 lane-max values (u32 bits, all >= +0) descending
  u32 sv = __float_as_uint(fmx);
#pragma unroll
  for (int k2 = 2; k2 <= 64; k2 <<= 1) {
#pragma unroll
    for (int jj = k2 >> 1; jj > 0; jj >>= 1) {
      u32 ov = (u32)__shfl_xor((int)sv, jj, 64);
      bool keepMax = ((lane & jj) == 0) == ((lane & k2) == 0);
      sv = (keepMax == (ov > sv)) ? ov : sv;
    }
  }
  u32 th = ((u32)__shfl((int)sv, 16, 64)) >> 16;
  u32 tau16 = (th > 0u) ? (th - 1u) : 0u;  // 1-quantum slack (superset)

  // Phase C: ballot-compact candidates with hi16(approx) >= tau16; exact keys
  int total = 0;
#pragma unroll
  for (int t = 0; t < 64; ++t) {
    u32 h = (t & 1) ? (denc16[t >> 1] >> 16) : (denc16[t >> 1] & 0xFFFFu);
    bool pred = (h >= tau16);
    u64 bal = __ballot(pred);
    if (bal != 0ull) {  // wave-uniform skip of empty slots
      int pos = total + (int)__builtin_amdgcn_mbcnt_hi(
                            (u32)(bal >> 32),
                            __builtin_amdgcn_mbcnt_lo((u32)bal, 0u));
      if (pred && pos < 64) {
        u32 enc = encdist(xi, yi, zi, sqi, p[lane + (t << 6)]);  // exact
        surv[wave][pos] = ((u64)enc << 32) | (u32)(4095 - (lane + (t << 6)));
      }
      total += (int)__popcll(bal);
    }
  }

  if (total <= 64) {
    // Phase D: sort survivors descending (zeros pad to the end), emit 1..16.
    u64 sk = (lane < total) ? surv[wave][lane] : 0ull;
#pragma unroll
    for (int k2 = 2; k2 <= 64; k2 <<= 1) {
#pragma unroll
      for (int jj = k2 >> 1; jj > 0; jj >>= 1) {
        u64 ok = __shfl_xor(sk, jj, 64);
        bool keepMax = ((lane & jj) == 0) == ((lane & k2) == 0);
        sk = (keepMax == (ok > sk)) ? ok : sk;
      }
    }
    if (lane >= 1 && lane < 17) {
      idxOut[((long long)(b * N + i)) * K + lane - 1] = 4095 - (int)(u32)sk;
    }
  } else {
    // Fallback (degenerate ties; never on this input): exact iterative
    // extraction; recomputes its own exact argmax first.
    u32 cmax = 0u; u32 ct = 0u;
#pragma unroll
    for (int t = 0; t < 64; ++t) {
      u32 enc = encdist(xi, yi, zi, sqi, p[lane + (t << 6)]);
      if (enc > cmax) { cmax = enc; ct = (u32)t; }
    }
    u64 elim = 0ull;
    for (int r = 0; r < 17; ++r) {
      u32 wmax = dpp_max64(cmax);
      u32 s_wmax = (u32)__builtin_amdgcn_readlane((int)wmax, 63);
      u64 mask = __ballot(cmax == s_wmax);
      int s_wj;
      if (__popcll(mask) == 1) {
        int l = (int)(__ffsll((long long)mask) - 1);
        int myj = lane + ((int)ct << 6);
        s_wj = __builtin_amdgcn_readlane(myj, l);
      } else {
        u32 jv = (cmax == s_wmax) ? (u32)(lane + ((int)ct << 6)) : 0xFFFFFFFFu;
#pragma unroll
        for (int off = 1; off < 64; off <<= 1) {
          u32 oj = (u32)__shfl_xor((int)jv, off, 64);
          jv = oj < jv ? oj : jv;
        }
        s_wj = (int)__builtin_amdgcn_readfirstlane((int)jv);
      }
      if (r > 0 && lane == 0)
        idxOut[((long long)(b * N + i)) * K + (r - 1)] = s_wj;
      if (r == 16) break;
      if (lane == (s_wj & 63)) {
        elim |= 1ull << (s_wj >> 6);
        cmax = 0u; ct = 0u;
        for (int t = 0; t < 64; ++t) {
          if (elim & (1ull << t)) continue;
          u32 enc = encdist(xi, yi, zi, sqi, p[lane + (t << 6)]);
          if (enc > cmax) { cmax = enc; ct = (u32)t; }
        }
      }
    }
  }
}

// ---- Abf = bf16(leaky(P)) : XCD-pair swizzled (1024 blocks x 256) ----
__global__ __launch_bounds__(256) void cvtA_kernel(const float* __restrict__ P,
                                                   unsigned short* __restrict__ Abf) {
  int b, rgrp;
  swz_batch(blockIdx.x, &b, &rgrp);
  int tid = threadIdx.x;
  size_t off = ((size_t)b * N + rgrp * 16 + (tid >> 4)) * C + (tid & 15) * 8;
  const float4* p4 = (const float4*)(P + off);
  float4 a = p4[0], c = p4[1];
  unsigned short u0 = f2bf(leaky(a.x)), u1 = f2bf(leaky(a.y));
  unsigned short u2 = f2bf(leaky(a.z)), u3 = f2bf(leaky(a.w));
  unsigned short u4 = f2bf(leaky(c.x)), u5 = f2bf(leaky(c.y));
  unsigned short u6 = f2bf(leaky(c.z)), u7 = f2bf(leaky(c.w));
  uint4 o;
  o.x = (u32)u0 | ((u32)u1 << 16);
  o.y = (u32)u2 | ((u32)u3 << 16);
  o.z = (u32)u4 | ((u32)u5 << 16);
  o.w = (u32)u6 | ((u32)u7 << 16);
  *(uint4*)(Abf + off) = o;
}

// ---- W (f32) -> bf16, all 3 blocks at once ----
__global__ __launch_bounds__(256) void cvtW_kernel(const float* __restrict__ Wc,
                                                   const float* __restrict__ Wg,
                                                   unsigned short* __restrict__ Wbf) {
  int e = blockIdx.x * 256 + threadIdx.x;  // 0..98303
  if (e < NB * C * C) Wbf[e] = f2bf(Wc[e]);
  else Wbf[e] = f2bf(Wg[e - NB * C * C]);
}

// ---- fused per-block-iter: gather-sum (bf16) + dual MFMA matmul + epilogue
// 256 blocks x 512 threads (8 waves), XCD-pair swizzled. Block = RB=64 rows.
// r23: only bCw (16 regs) is prefetched across the gather; the bGw loads are
// issued AFTER the gather barrier, their L2 latency hidden under the first
// MFMA loop (LDS+bCw only). Cuts peak gather-phase VGPR by ~16, targeting
// <=64 (8 waves/SIMD * 4 blocks/CU via the r22 union's 38.9KB LDS).
__global__ __launch_bounds__(512) void fused_kernel(
    const float* __restrict__ Pcur, const unsigned short* __restrict__ Abf,
    const int* __restrict__ idx,
    const unsigned short* __restrict__ Wcbf, const unsigned short* __restrict__ Wgbf,
    const float* __restrict__ bc, const float* __restrict__ bg,
    float* __restrict__ Pnxt, unsigned short* __restrict__ AbfN) {
  union SmemU {
    struct { unsigned short Al[RB][136]; unsigned short Sl[RB][136]; } ab;  // 34.8 KB
    __attribute__((aligned(16))) float Pst[RB][132];                        // 33.8 KB
  };
  __shared__ SmemU su;       // 34.8 KB (union)
  __shared__ int ji[RB * K]; // 4 KB
  int bb, rgrp;
  swz_batch(blockIdx.x, &bb, &rgrp);      // 256 blocks: rgrp 0..63
  int row0 = bb * N + rgrp * RB;          // global row
  int tid = threadIdx.x;
  ji[tid] = idx[row0 * K + tid];          // RB*K = 1024 = 2x blockDim
  ji[tid + 512] = idx[row0 * K + tid + 512];
  __syncthreads();

  // batch base for neighbor indices (idx entries are within-batch!)
  const unsigned short* AbfB = Abf + ((size_t)bb << 12) * C;

  // prefetch ONLY the center-conv B-operands across the gather (16 regs)
  int lane = tid & 63, wave = tid >> 6;  // 8 waves
  int lrow = lane & 15;
  int kgrp = (lane >> 4) * 8;
  int ct = wave;
  const unsigned short* wcp = Wcbf + (size_t)(ct * 16 + lrow) * C + kgrp;
  const unsigned short* wgp = Wgbf + (size_t)(ct * 16 + lrow) * C + kgrp;
  short8_t bCw[4];
#pragma unroll
  for (int ks = 0; ks < 4; ++ks) {
    bCw[ks] = *(const short8_t*)(wcp + ks * 32);
  }

  // stage the block's A-tile (64 rows x 256B = 16KB) into LDS: 2 x 16B/thread
#pragma unroll
  for (int it = 0; it < 2; ++it) {
    int item = tid + it * 512;
    int r = item >> 4, g = item & 15;
    *(uint4*)(&su.ab.Al[r][g * 8]) =
        *(const uint4*)(Abf + (size_t)(row0 + r) * C + g * 8);
  }

  // gather: item (r,g) sums 8 cols [g*8, g*8+8) of row r over 16 neighbors;
  // 64 rows x 16 groups = 1024 items, 2 per thread
#pragma unroll
  for (int it = 0; it < 2; ++it) {
    int item = tid + it * 512;
    int r = item >> 4, g = item & 15;  // r 0..63
    float s0 = 0.f, s1 = 0.f, s2 = 0.f, s3 = 0.f, s4 = 0.f, s5 = 0.f, s6 = 0.f, s7 = 0.f;
#pragma unroll
    for (int t = 0; t < K; ++t) {
      int j = ji[(r << 4) + t];
      uint4 v = *(const uint4*)(AbfB + (size_t)j * C + g * 8);
      s0 += bflo(v.x); s1 += bfhi(v.x);
      s2 += bflo(v.y); s3 += bfhi(v.y);
      s4 += bflo(v.z); s5 += bfhi(v.z);
      s6 += bflo(v.w); s7 += bfhi(v.w);
    }
    uint4 o;
    o.x = (u32)f2bf(s0) | ((u32)f2bf(s1) << 16);
    o.y = (u32)f2bf(s2) | ((u32)f2bf(s3) << 16);
    o.z = (u32)f2bf(s4) | ((u32)f2bf(s5) << 16);
    o.w = (u32)f2bf(s6) | ((u32)f2bf(s7) << 16);
    *(uint4*)(&su.ab.Sl[r][g * 8]) = o;
  }
  __syncthreads();

  // issue the group-conv B-operand loads now; latency hidden under MFMA-1
  short8_t bGw[4];
#pragma unroll
  for (int ks = 0; ks < 4; ++ks) {
    bGw[ks] = *(const short8_t*)(wgp + ks * 32);
  }

  // MFMA: wave = col-tile ct (16 cols); 4 row-tiles (rows rt*16..rt*16+15).
  // A row = lane&15, k-chunk = (lane>>4)*8 ; B col = lane&15, same k-chunk.
  f32x4 acc[4];
#pragma unroll
  for (int rt = 0; rt < 4; ++rt) acc[rt] = (f32x4){0.f, 0.f, 0.f, 0.f};
#pragma unroll
  for (int ks = 0; ks < 4; ++ks) {
#pragma unroll
    for (int rt = 0; rt < 4; ++rt) {
      short8_t av = *(const short8_t*)(&su.ab.Al[rt * 16 + lrow][kgrp + ks * 32]);
      acc[rt] = __builtin_amdgcn_mfma_f32_16x16x32_bf16(av, bCw[ks], acc[rt], 0, 0, 0);
    }
  }
#pragma unroll
  for (int ks = 0; ks < 4; ++ks) {
#pragma unroll
    for (int rt = 0; rt < 4; ++rt) {
      short8_t sv = *(const short8_t*)(&su.ab.Sl[rt * 16 + lrow][kgrp + ks * 32]);
      acc[rt] = __builtin_amdgcn_mfma_f32_16x16x32_bf16(sv, bGw[ks], acc[rt], 0, 0, 0);
    }
  }
  __syncthreads();  // all waves done reading Al/Sl before Pst overwrites them

  // stage fragments: D row=(lane>>4)*4+q, col=lane&15 (within 16x16 tile)
  {
    int colw = ct * 16 + lrow;
    int rbase = (lane >> 4) * 4;
#pragma unroll
    for (int rt = 0; rt < 4; ++rt) {
#pragma unroll
      for (int q = 0; q < 4; ++q) {
        su.Pst[rt * 16 + rbase + q][colw] = acc[rt][q];
      }
    }
  }
  __syncthreads();

  // coalesced epilogue: item -> (row, 8 cols); float4/uint4 global I/O
#pragma unroll
  for (int it = 0; it < 2; ++it) {
    int item = tid + it * 512;
    int er = item >> 4;
    int ec8 = (item & 15) * 8;
    size_t goff = (size_t)(row0 + er) * C + ec8;
    float4 pv0 = *(const float4*)&Pcur[goff];
    float4 pv1 = *(const float4*)&Pcur[goff + 4];
    float4 av = *(const float4*)&su.Pst[er][ec8];
    float4 aw = *(const float4*)&su.Pst[er][ec8 + 4];
    float4 bcv0 = *(const float4*)&bc[ec8];
    float4 bcv1 = *(const float4*)&bc[ec8 + 4];
    float4 bgv0 = *(const float4*)&bg[ec8];
    float4 bgv1 = *(const float4*)&bg[ec8 + 4];
    float4 o0, o1;
    o0.x = (av.x + (bcv0.x + 16.0f * bgv0.x)) * (1.0f / 17.0f) + pv0.x;
    o0.y = (av.y + (bcv0.y + 16.0f * bgv0.y)) * (1.0f / 17.0f) + pv0.y;
    o0.z = (av.z + (bcv0.z + 16.0f * bgv0.z)) * (1.0f / 17.0f) + pv0.z;
    o0.w = (av.w + (bcv0.w + 16.0f * bgv0.w)) * (1.0f / 17.0f) + pv0.w;
    o1.x = (aw.x + (bcv1.x + 16.0f * bgv1.x)) * (1.0f / 17.0f) + pv1.x;
    o1.y = (aw.y + (bcv1.y + 16.0f * bgv1.y)) * (1.0f / 17.0f) + pv1.y;
    o1.z = (aw.z + (bcv1.z + 16.0f * bgv1.z)) * (1.0f / 17.0f) + pv1.z;
    o1.w = (aw.w + (bcv1.w + 16.0f * bgv1.w)) * (1.0f / 17.0f) + pv1.w;
    *(float4*)&Pnxt[goff] = o0;
    *(float4*)&Pnxt[goff + 4] = o1;
    if (AbfN) {
      uint4 ob;
      ob.x = (u32)f2bf(leaky(o0.x)) | ((u32)f2bf(leaky(o0.y)) << 16);
      ob.y = (u32)f2bf(leaky(o0.z)) | ((u32)f2bf(leaky(o0.w)) << 16);
      ob.z = (u32)f2bf(leaky(o1.x)) | ((u32)f2bf(leaky(o1.y)) << 16);
      ob.w = (u32)f2bf(leaky(o1.z)) | ((u32)f2bf(leaky(o1.w)) << 16);
      *(uint4*)(AbfN + goff) = ob;
    }
  }
}

extern "C" void kernel_launch(void* const* d_in, const int* in_sizes, int n_in,
                              void* d_out, int out_size, void* d_ws, size_t ws_size,
                              hipStream_t stream) {
  const float* xyz = (const float*)d_in[0];
  const float* pts = (const float*)d_in[1];
  const float* Wc = (const float*)d_in[5];
  const float* bc = (const float*)d_in[6];
  const float* Wg = (const float*)d_in[7];
  const float* bg = (const float*)d_in[8];

  const size_t PE = (size_t)B * N * C;            // 2097152 elements
  const size_t idxB = (size_t)B * N * K * 4;      // 1 MB
  const size_t WbfB = (size_t)2 * NB * C * C * 2; // 192 KB
  char* ws = (char*)d_ws;
  float* Pa            = (float*)ws;                                  // 8 MB
  int* idx             = (int*)(ws + PE * 4);                         // 1 MB
  unsigned short* Abf0 = (unsigned short*)(ws + PE * 4 + idxB);       // 4 MB
  unsigned short* Wbf  = (unsigned short*)(ws + PE * 4 + idxB + PE * 2);
  unsigned short* Abf1 = (unsigned short*)(ws + PE * 4 + idxB + PE * 2 + WbfB);
  unsigned short* Wcbf = Wbf;
  unsigned short* Wgbf = Wbf + (size_t)NB * C * C;
  const size_t need = PE * 4 + idxB + PE * 2 + WbfB + PE * 2;  // 17.2 MB
  const bool fusedAbf = (ws_size >= need);

  hipLaunchKernelGGL(cvtW_kernel, dim3((2 * NB * C * C) / 256), dim3(256), 0, stream,
                     Wc, Wg, Wbf);
  hipLaunchKernelGGL(cvtA_kernel, dim3(1024), dim3(256), 0, stream, pts, Abf0);
  hipLaunchKernelGGL(knn_kernel, dim3(2048), dim3(512), 0, stream, xyz, idx);

  // ping-pong: pts (read-only) -> d_out -> Pa -> d_out
  const float* cur = pts;
  float* nxt = (float*)d_out;
  unsigned short* AbfCur = Abf0;
  unsigned short* AbfNxt = fusedAbf ? Abf1 : Abf0;
  for (int i = 0; i < NB; ++i) {
    if (!fusedAbf && i > 0) {
      hipLaunchKernelGGL(cvtA_kernel, dim3(1024), dim3(256), 0, stream, cur, Abf0);
      AbfCur = Abf0;
    }
    unsigned short* an = (fusedAbf && i < NB - 1) ? AbfNxt : (unsigned short*)nullptr;
    hipLaunchKernelGGL(fused_kernel, dim3((B * N) / RB), dim3(512), 0, stream,
                       cur, AbfCur, idx, Wcbf + (size_t)i * C * C, Wgbf + (size_t)i * C * C,
                       bc + (size_t)i * C, bg + (size_t)i * C, nxt, an);
    cur = nxt;
    nxt = (i == 0) ? Pa : (float*)d_out;
    if (fusedAbf) { unsigned short* ta = AbfCur; AbfCur = AbfNxt; AbfNxt = ta; }
  }
}